// Round 1
// baseline (15038.739 us; speedup 1.0000x reference)
//
#include <hip/hip_runtime.h>
#include <hip/hip_bf16.h>
#include <math.h>

// ---------------- problem constants ----------------
#define T_    512
#define B_    256
#define INP_  128
#define HID_  256
#define OUT_  64
#define DT_   0.1f
#define CPL_  0.1f

typedef __attribute__((ext_vector_type(8))) short          bf16x8;
typedef __attribute__((ext_vector_type(4))) float          f32x4;
typedef __attribute__((ext_vector_type(4))) unsigned short u16x4;

// ---------------- ws layout (ushort units for bf16 region) ----------------
#define WH     0        // W_h_w        256x256
#define WTAUH  65536    // W_tau_h_w    256x256
#define WZR    131072   // W_z_real_w   256x256
#define WZI    196608   // W_z_imag_w   256x256
#define WTAUZ  262144   // W_tau_z_w    256x256
#define H2Z    327680   // h2z_w * CPL  256x256
#define Z2H    393216   // z2h_w * CPL  256x256
#define UH     458752   // U_h_w        256x128
#define UZ     491520   // U_z_w        256x128
#define OH     524288   // out_h_w      64x256
#define OZ     540672   // out_z_w      64x256
#define NW_TOTAL 557056
#define BIAS_OFF_BYTES (NW_TOTAL * 2)
// bias arrays (float offsets within bias region)
#define BT_H    0     // tanh-arg bias for h path   (= W_h_b)
#define BTAU_H  256   // tau_h sigmoid-arg bias     (= W_tau_h_b)
#define BH_TOT  512   // U_h_b + b_h + CPL*z2h_b
#define BT_ZR   768   // = W_z_real_b
#define BT_ZI   1024  // = W_z_imag_b
#define BTAU_Z  1280  // = W_tau_z_b
#define BZR_TOT 1536  // U_z_b + b_z_real + CPL*h2z_b
#define BZI_TOT 1792  // U_z_b + b_z_imag + CPL*h2z_b
#define BY      2048  // out_h_b + out_z_b  (64)

// fp32 -> bf16, round-to-nearest-even
__device__ __forceinline__ unsigned short f2bf(float f) {
    unsigned int u = __float_as_uint(f);
    u += 0x7fffu + ((u >> 16) & 1u);
    return (unsigned short)(u >> 16);
}

__device__ __forceinline__ float sigmoid_fast(float x) {
    return 1.0f / (1.0f + __expf(-x));
}
__device__ __forceinline__ float tanh_fast(float x) {
    float e = __expf(2.0f * x);
    return 1.0f - 2.0f / (e + 1.0f);
}

// ---------------- prep: weights fp32 -> bf16 into ws ----------------
__global__ void prep_weights(const float* __restrict__ Wh,   const float* __restrict__ Wtauh,
                             const float* __restrict__ Wzr,  const float* __restrict__ Wzi,
                             const float* __restrict__ Wtauz,const float* __restrict__ h2z,
                             const float* __restrict__ z2h,  const float* __restrict__ Uh,
                             const float* __restrict__ Uz,   const float* __restrict__ oh,
                             const float* __restrict__ oz,   unsigned short* __restrict__ ws) {
    int i = blockIdx.x * 256 + threadIdx.x;
    if (i >= NW_TOTAL) return;
    float v;
    if      (i < WTAUH) v = Wh[i - WH];
    else if (i < WZR)   v = Wtauh[i - WTAUH];
    else if (i < WZI)   v = Wzr[i - WZR];
    else if (i < WTAUZ) v = Wzi[i - WZI];
    else if (i < H2Z)   v = Wtauz[i - WTAUZ];
    else if (i < Z2H)   v = h2z[i - H2Z] * CPL_;   // fold coupling into weights
    else if (i < UH)    v = z2h[i - Z2H] * CPL_;
    else if (i < UZ)    v = Uh[i - UH];
    else if (i < OH)    v = Uz[i - UZ];
    else if (i < OZ)    v = oh[i - OH];
    else                v = oz[i - OZ];
    ws[i] = f2bf(v);
}

// ---------------- prep: folded biases (fp32) ----------------
__global__ void prep_bias(const float* __restrict__ Whb,  const float* __restrict__ Wtauhb,
                          const float* __restrict__ Uhb,  const float* __restrict__ bh,
                          const float* __restrict__ z2hb, const float* __restrict__ Wzrb,
                          const float* __restrict__ Wzib, const float* __restrict__ Wtauzb,
                          const float* __restrict__ Uzb,  const float* __restrict__ bzr,
                          const float* __restrict__ bzi,  const float* __restrict__ h2zb,
                          const float* __restrict__ ohb,  const float* __restrict__ ozb,
                          float* __restrict__ bias) {
    int n = threadIdx.x;
    if (n < 256) {
        bias[BT_H + n]    = Whb[n];
        bias[BTAU_H + n]  = Wtauhb[n];
        bias[BH_TOT + n]  = Uhb[n] + bh[n] + CPL_ * z2hb[n];
        bias[BT_ZR + n]   = Wzrb[n];
        bias[BT_ZI + n]   = Wzib[n];
        bias[BTAU_Z + n]  = Wtauzb[n];
        bias[BZR_TOT + n] = Uzb[n] + bzr[n] + CPL_ * h2zb[n];
        bias[BZI_TOT + n] = Uzb[n] + bzi[n] + CPL_ * h2zb[n];
        if (n < 64) bias[BY + n] = ohb[n] + ozb[n];
    }
}

// GEMM over K=256: O[m][n] += sum_k S[m][k] * W[n][k], state A-frags from swizzled LDS,
// weight B-frags streamed from global (L2-resident bf16).
__device__ __forceinline__ f32x4 gemmH(const unsigned short* sA, const unsigned short* wB,
                                       int n, int m, int hi) {
    f32x4 acc = {0.f, 0.f, 0.f, 0.f};
    const char* base = (const char*)sA;
    const int xm = (m & 7) << 4;
#pragma unroll
    for (int kt = 0; kt < 8; ++kt) {
        bf16x8 a = *(const bf16x8*)(base + ((m * 512 + kt * 64 + hi * 16) ^ xm));
        bf16x8 b = *(const bf16x8*)(wB + (n << 8) + kt * 32 + hi * 8);
        acc = __builtin_amdgcn_mfma_f32_16x16x32_bf16(a, b, acc, 0, 0, 0);
    }
    return acc;
}

// GEMM over K=128 (x-input GEMMs)
__device__ __forceinline__ f32x4 gemmX(const unsigned short* sA, const unsigned short* wB,
                                       int n, int m, int hi) {
    f32x4 acc = {0.f, 0.f, 0.f, 0.f};
    const char* base = (const char*)sA;
    const int xm = (m & 7) << 4;
#pragma unroll
    for (int kt = 0; kt < 4; ++kt) {
        bf16x8 a = *(const bf16x8*)(base + ((m * 256 + kt * 64 + hi * 16) ^ xm));
        bf16x8 b = *(const bf16x8*)(wB + (n << 7) + kt * 32 + hi * 8);
        acc = __builtin_amdgcn_mfma_f32_16x16x32_bf16(a, b, acc, 0, 0, 0);
    }
    return acc;
}

// ---------------- main recurrent kernel ----------------
// grid: 16 blocks (16 batch rows each), 512 threads = 8 waves.
// wave w owns output-column tiles {2w, 2w+1} (16 cols each) of HID=256.
__launch_bounds__(512, 1)
__global__ void twistor_main(const float* __restrict__ x, const unsigned short* __restrict__ ws,
                             float* __restrict__ y) {
    // bf16 state tiles [16 rows][256 cols], XOR-swizzled (byte ^= (row&7)<<4)
    __shared__ unsigned short s_h[4096], s_zr[4096], s_zi[4096], s_za[4096];
    __shared__ unsigned short s_x[2048];   // x_t tile [16][128] bf16, swizzled

    const int tid  = threadIdx.x;
    const int lane = tid & 63;
    const int w    = tid >> 6;
    const int m16  = lane & 15;
    const int hi   = lane >> 4;
    const int brow0 = blockIdx.x * 16;
    const float* bias = (const float*)((const char*)ws + BIAS_OFF_BYTES);

    // zero state LDS
    for (int i = tid; i < 4096; i += 512) { s_h[i] = 0; s_zr[i] = 0; s_zi[i] = 0; s_za[i] = 0; }
    // stage x_0 (fp32 global -> bf16 LDS, swizzled)
    {
        int m = tid >> 5, c4 = (tid & 31) * 4;
        float4 v = *(const float4*)(x + ((size_t)(brow0 + m) * INP_ + c4));
        u16x4 p; p.x = f2bf(v.x); p.y = f2bf(v.y); p.z = f2bf(v.z); p.w = f2bf(v.w);
        int byte = (m * 256 + c4 * 2) ^ ((m & 7) << 4);
        *(u16x4*)((char*)s_x + byte) = p;
    }
    __syncthreads();

    // per-lane folded biases for the two owned column tiles
    const int ntA = 2 * w, ntB = 2 * w + 1;
    const int nA = ntA * 16 + m16, nB = ntB * 16 + m16;
    float bthh[2]  = {bias[BT_H + nA],    bias[BT_H + nB]};
    float btauh[2] = {bias[BTAU_H + nA],  bias[BTAU_H + nB]};
    float bht[2]   = {bias[BH_TOT + nA],  bias[BH_TOT + nB]};
    float btzr[2]  = {bias[BT_ZR + nA],   bias[BT_ZR + nB]};
    float btzi[2]  = {bias[BT_ZI + nA],   bias[BT_ZI + nB]};
    float btauz[2] = {bias[BTAU_Z + nA],  bias[BTAU_Z + nB]};
    float bzrt[2]  = {bias[BZR_TOT + nA], bias[BZR_TOT + nB]};
    float bzit[2]  = {bias[BZI_TOT + nA], bias[BZI_TOT + nB]};
    float by_ = (w < 4) ? bias[BY + w * 16 + m16] : 0.f;

    // fp32 state in C/D fragment layout: element (row hi*4+j, col nt*16+m16)
    float h_[2][4]  = {{0, 0, 0, 0}, {0, 0, 0, 0}};
    float zr_[2][4] = {{0, 0, 0, 0}, {0, 0, 0, 0}};
    float zi_[2][4] = {{0, 0, 0, 0}, {0, 0, 0, 0}};

    for (int t = 0; t < T_; ++t) {
        float hn_[2][4], zrn_[2][4], zin_[2][4], zan_[2][4];
#pragma unroll
        for (int u = 0; u < 2; ++u) {
            const int n = (2 * w + u) * 16 + m16;
            f32x4 g_th  = gemmH(s_h,  ws + WH,    n, m16, hi);
            f32x4 g_tau = gemmH(s_h,  ws + WTAUH, n, m16, hi);
            f32x4 g_h2z = gemmH(s_h,  ws + H2Z,   n, m16, hi);
            f32x4 g_z2h = gemmH(s_zr, ws + Z2H,   n, m16, hi);
            f32x4 g_tzr = gemmH(s_zr, ws + WZR,   n, m16, hi);
            f32x4 g_tzi = gemmH(s_zi, ws + WZI,   n, m16, hi);
            f32x4 g_tz  = gemmH(s_za, ws + WTAUZ, n, m16, hi);
            f32x4 g_ux  = gemmX(s_x,  ws + UH,    n, m16, hi);
            f32x4 g_uz  = gemmX(s_x,  ws + UZ,    n, m16, hi);
#pragma unroll
            for (int j = 0; j < 4; ++j) {
                float th  = fminf(fmaxf(sigmoid_fast(g_tau[j] + btauh[u]), 0.01f), 1.0f) + 1e-6f;
                float dh  = (-h_[u][j] + tanh_fast(g_th[j] + bthh[u]) + g_ux[j] + bht[u] + g_z2h[j]) / th;
                hn_[u][j] = h_[u][j] + DT_ * dh;
                float tz  = fminf(fmaxf(sigmoid_fast(g_tz[j] + btauz[u]), 0.01f), 1.0f) + 1e-6f;
                float cm  = g_uz[j] + g_h2z[j];
                float dzr = (-zr_[u][j] + tanh_fast(g_tzr[j] + btzr[u]) + cm + bzrt[u]) / tz;
                float dzi = (-zi_[u][j] + tanh_fast(g_tzi[j] + btzi[u]) + cm + bzit[u]) / tz;
                zrn_[u][j] = zr_[u][j] + DT_ * dzr;
                zin_[u][j] = zi_[u][j] + DT_ * dzi;
                zan_[u][j] = sqrtf(zrn_[u][j] * zrn_[u][j] + zin_[u][j] * zin_[u][j] + 1e-24f);
            }
        }
        __syncthreads();   // all waves done READING old state LDS
        // write new bf16 state (swizzled scatter, 2-way-free bank pattern)
#pragma unroll
        for (int u = 0; u < 2; ++u) {
            const int n = (2 * w + u) * 16 + m16;
#pragma unroll
            for (int j = 0; j < 4; ++j) {
                const int mr = hi * 4 + j;
                const int byte = (mr * 512 + n * 2) ^ ((mr & 7) << 4);
                *(unsigned short*)((char*)s_h + byte)  = f2bf(hn_[u][j]);
                *(unsigned short*)((char*)s_zr + byte) = f2bf(zrn_[u][j]);
                *(unsigned short*)((char*)s_zi + byte) = f2bf(zin_[u][j]);
                *(unsigned short*)((char*)s_za + byte) = f2bf(zan_[u][j]);
            }
        }
        // stage x_{t+1}
        if (t + 1 < T_) {
            int m = tid >> 5, c4 = (tid & 31) * 4;
            float4 v = *(const float4*)(x + ((size_t)((t + 1) * B_ + brow0 + m) * INP_ + c4));
            u16x4 p; p.x = f2bf(v.x); p.y = f2bf(v.y); p.z = f2bf(v.z); p.w = f2bf(v.w);
            int byte = (m * 256 + c4 * 2) ^ ((m & 7) << 4);
            *(u16x4*)((char*)s_x + byte) = p;
        }
        // commit registers
#pragma unroll
        for (int u = 0; u < 2; ++u)
#pragma unroll
            for (int j = 0; j < 4; ++j) {
                h_[u][j] = hn_[u][j]; zr_[u][j] = zrn_[u][j]; zi_[u][j] = zin_[u][j];
            }
        __syncthreads();   // new state visible

        // output GEMM: y_t = h_n @ out_h^T + zr_n @ out_z^T + by (waves 0..3, N=64)
        if (w < 4) {
            f32x4 acc = {0.f, 0.f, 0.f, 0.f};
            const int n = w * 16 + m16;
            const char* hb = (const char*)s_h;
            const char* zb = (const char*)s_zr;
            const int xm = (m16 & 7) << 4;
#pragma unroll
            for (int kt = 0; kt < 8; ++kt) {
                bf16x8 a = *(const bf16x8*)(hb + ((m16 * 512 + kt * 64 + hi * 16) ^ xm));
                bf16x8 b = *(const bf16x8*)(ws + OH + (n << 8) + kt * 32 + hi * 8);
                acc = __builtin_amdgcn_mfma_f32_16x16x32_bf16(a, b, acc, 0, 0, 0);
            }
#pragma unroll
            for (int kt = 0; kt < 8; ++kt) {
                bf16x8 a = *(const bf16x8*)(zb + ((m16 * 512 + kt * 64 + hi * 16) ^ xm));
                bf16x8 b = *(const bf16x8*)(ws + OZ + (n << 8) + kt * 32 + hi * 8);
                acc = __builtin_amdgcn_mfma_f32_16x16x32_bf16(a, b, acc, 0, 0, 0);
            }
#pragma unroll
            for (int j = 0; j < 4; ++j) {
                const int mr = hi * 4 + j;
                y[((size_t)t * B_ + brow0 + mr) * OUT_ + n] = acc[j] + by_;
            }
        }
    }
}

extern "C" void kernel_launch(void* const* d_in, const int* in_sizes, int n_in,
                              void* d_out, int out_size, void* d_ws, size_t ws_size,
                              hipStream_t stream) {
    const float* x = (const float*)d_in[0];
    unsigned short* ws = (unsigned short*)d_ws;
    float* bias = (float*)((char*)d_ws + BIAS_OFF_BYTES);

    prep_weights<<<(NW_TOTAL + 255) / 256, 256, 0, stream>>>(
        (const float*)d_in[1],  /* W_h_w */
        (const float*)d_in[5],  /* W_tau_h_w */
        (const float*)d_in[8],  /* W_z_real_w */
        (const float*)d_in[10], /* W_z_imag_w */
        (const float*)d_in[14], /* W_tau_z_w */
        (const float*)d_in[18], /* h2z_w */
        (const float*)d_in[20], /* z2h_w */
        (const float*)d_in[3],  /* U_h_w */
        (const float*)d_in[12], /* U_z_w */
        (const float*)d_in[22], /* out_h_w */
        (const float*)d_in[24], /* out_z_w */
        ws);
    prep_bias<<<1, 256, 0, stream>>>(
        (const float*)d_in[2],  /* W_h_b */
        (const float*)d_in[6],  /* W_tau_h_b */
        (const float*)d_in[4],  /* U_h_b */
        (const float*)d_in[7],  /* b_h */
        (const float*)d_in[21], /* z2h_b */
        (const float*)d_in[9],  /* W_z_real_b */
        (const float*)d_in[11], /* W_z_imag_b */
        (const float*)d_in[15], /* W_tau_z_b */
        (const float*)d_in[13], /* U_z_b */
        (const float*)d_in[16], /* b_z_real */
        (const float*)d_in[17], /* b_z_imag */
        (const float*)d_in[19], /* h2z_b */
        (const float*)d_in[23], /* out_h_b */
        (const float*)d_in[25], /* out_z_b */
        bias);
    twistor_main<<<16, 512, 0, stream>>>(x, ws, (float*)d_out);
}

// Round 2
// 14971.532 us; speedup vs baseline: 1.0045x; 1.0045x over previous
//
#include <hip/hip_runtime.h>
#include <hip/hip_bf16.h>
#include <math.h>

// ---------------- problem constants ----------------
#define T_    512
#define B_    256
#define INP_  128
#define HID_  256
#define OUT_  64
#define DT_   0.1f
#define CPL_  0.1f

typedef __attribute__((ext_vector_type(8))) short          bf16x8;
typedef __attribute__((ext_vector_type(4))) float          f32x4;
typedef __attribute__((ext_vector_type(4))) unsigned short u16x4;

// ---------------- ws layout (ushort units for bf16 region) ----------------
#define WH     0        // W_h_w        256x256
#define WTAUH  65536    // W_tau_h_w    256x256
#define WZR    131072   // W_z_real_w   256x256
#define WZI    196608   // W_z_imag_w   256x256
#define WTAUZ  262144   // W_tau_z_w    256x256
#define H2Z    327680   // h2z_w * CPL  256x256
#define Z2H    393216   // z2h_w * CPL  256x256
#define UH     458752   // U_h_w        256x128
#define UZ     491520   // U_z_w        256x128
#define OH     524288   // out_h_w      64x256
#define OZ     540672   // out_z_w      64x256
#define NW_TOTAL 557056
#define BIAS_OFF_BYTES (NW_TOTAL * 2)
// bias arrays (float offsets within bias region)
#define BT_H    0     // tanh-arg bias for h path   (= W_h_b)
#define BTAU_H  256   // tau_h sigmoid-arg bias     (= W_tau_h_b)
#define BH_TOT  512   // U_h_b + b_h + CPL*z2h_b
#define BT_ZR   768   // = W_z_real_b
#define BT_ZI   1024  // = W_z_imag_b
#define BTAU_Z  1280  // = W_tau_z_b
#define BZR_TOT 1536  // U_z_b + b_z_real + CPL*h2z_b
#define BZI_TOT 1792  // U_z_b + b_z_imag + CPL*h2z_b
#define BY      2048  // out_h_b + out_z_b  (64)

// fp32 -> bf16, round-to-nearest-even
__device__ __forceinline__ unsigned short f2bf(float f) {
    unsigned int u = __float_as_uint(f);
    u += 0x7fffu + ((u >> 16) & 1u);
    return (unsigned short)(u >> 16);
}

__device__ __forceinline__ float rcp_(float x) { return __builtin_amdgcn_rcpf(x); }
__device__ __forceinline__ float sigmoid_fast(float x) {
    return rcp_(1.0f + __expf(-x));
}
__device__ __forceinline__ float tanh_fast(float x) {
    return 1.0f - 2.0f * rcp_(__expf(2.0f * x) + 1.0f);
}

// ---------------- prep: weights fp32 -> bf16 into ws ----------------
__global__ void prep_weights(const float* __restrict__ Wh,   const float* __restrict__ Wtauh,
                             const float* __restrict__ Wzr,  const float* __restrict__ Wzi,
                             const float* __restrict__ Wtauz,const float* __restrict__ h2z,
                             const float* __restrict__ z2h,  const float* __restrict__ Uh,
                             const float* __restrict__ Uz,   const float* __restrict__ oh,
                             const float* __restrict__ oz,   unsigned short* __restrict__ ws) {
    int i = blockIdx.x * 256 + threadIdx.x;
    if (i >= NW_TOTAL) return;
    float v;
    if      (i < WTAUH) v = Wh[i - WH];
    else if (i < WZR)   v = Wtauh[i - WTAUH];
    else if (i < WZI)   v = Wzr[i - WZR];
    else if (i < WTAUZ) v = Wzi[i - WZI];
    else if (i < H2Z)   v = Wtauz[i - WTAUZ];
    else if (i < Z2H)   v = h2z[i - H2Z] * CPL_;   // fold coupling into weights
    else if (i < UH)    v = z2h[i - Z2H] * CPL_;
    else if (i < UZ)    v = Uh[i - UH];
    else if (i < OH)    v = Uz[i - UZ];
    else if (i < OZ)    v = oh[i - OH];
    else                v = oz[i - OZ];
    ws[i] = f2bf(v);
}

// ---------------- prep: folded biases (fp32) ----------------
__global__ void prep_bias(const float* __restrict__ Whb,  const float* __restrict__ Wtauhb,
                          const float* __restrict__ Uhb,  const float* __restrict__ bh,
                          const float* __restrict__ z2hb, const float* __restrict__ Wzrb,
                          const float* __restrict__ Wzib, const float* __restrict__ Wtauzb,
                          const float* __restrict__ Uzb,  const float* __restrict__ bzr,
                          const float* __restrict__ bzi,  const float* __restrict__ h2zb,
                          const float* __restrict__ ohb,  const float* __restrict__ ozb,
                          float* __restrict__ bias) {
    int n = threadIdx.x;
    if (n < 256) {
        bias[BT_H + n]    = Whb[n];
        bias[BTAU_H + n]  = Wtauhb[n];
        bias[BH_TOT + n]  = Uhb[n] + bh[n] + CPL_ * z2hb[n];
        bias[BT_ZR + n]   = Wzrb[n];
        bias[BT_ZI + n]   = Wzib[n];
        bias[BTAU_Z + n]  = Wtauzb[n];
        bias[BZR_TOT + n] = Uzb[n] + bzr[n] + CPL_ * h2zb[n];
        bias[BZI_TOT + n] = Uzb[n] + bzi[n] + CPL_ * h2zb[n];
        if (n < 64) bias[BY + n] = ohb[n] + ozb[n];
    }
}

// Load the 8 A-fragments (full K=256) for one state tile from swizzled LDS, once.
__device__ __forceinline__ void loadA8(const unsigned short* s, int m16, int hi, bf16x8* a) {
    const char* base = (const char*)s;
    const int xm = (m16 & 7) << 4;
#pragma unroll
    for (int kt = 0; kt < 8; ++kt)
        a[kt] = *(const bf16x8*)(base + ((m16 * 512 + kt * 64 + hi * 16) ^ xm));
}

// GEMM with A resident in registers; B-frags batch-loaded from global (L2-resident).
// SH: log2(row stride in ushorts) of the weight matrix (8 for K=256, 7 for K=128).
template<int NKT, int SH>
__device__ __forceinline__ void gemmB(const bf16x8* a, const unsigned short* __restrict__ wB,
                                      int n, int hi, f32x4& acc) {
    bf16x8 b[NKT];
#pragma unroll
    for (int kt = 0; kt < NKT; ++kt)
        b[kt] = *(const bf16x8*)(wB + (n << SH) + kt * 32 + hi * 8);
#pragma unroll
    for (int kt = 0; kt < NKT; ++kt)
        acc = __builtin_amdgcn_mfma_f32_16x16x32_bf16(a[kt], b[kt], acc, 0, 0, 0);
}

// x A-fragment straight from global fp32 (row = batch row, 8 consecutive cols)
__device__ __forceinline__ bf16x8 loadXfrag(const float* __restrict__ xrow, int off) {
    float4 v0 = *(const float4*)(xrow + off);
    float4 v1 = *(const float4*)(xrow + off + 4);
    bf16x8 r;
    r[0] = (short)f2bf(v0.x); r[1] = (short)f2bf(v0.y);
    r[2] = (short)f2bf(v0.z); r[3] = (short)f2bf(v0.w);
    r[4] = (short)f2bf(v1.x); r[5] = (short)f2bf(v1.y);
    r[6] = (short)f2bf(v1.z); r[7] = (short)f2bf(v1.w);
    return r;
}

// ---------------- main recurrent kernel ----------------
// grid: 16 blocks (16 batch rows each), 512 threads = 8 waves (2/SIMD).
// wave w owns column tiles {2w, 2w+1}; state double-buffered in LDS (1 barrier/step).
__launch_bounds__(512, 2)
__global__ void twistor_main(const float* __restrict__ x, const unsigned short* __restrict__ ws,
                             float* __restrict__ y) {
    // state buffers: [parity][state h,zr,zi,za][16 rows x 256 cols bf16, XOR-swizzled]
    __shared__ unsigned short sbuf[2][4][4096];   // 64 KiB

    const int tid  = threadIdx.x;
    const int lane = tid & 63;
    const int w    = tid >> 6;
    const int m16  = lane & 15;
    const int hi   = lane >> 4;
    const int brow0 = blockIdx.x * 16;
    const float* bias = (const float*)((const char*)ws + BIAS_OFF_BYTES);

    // zero both state buffers
    for (int i = tid; i < 2 * 4 * 4096; i += 512) ((unsigned short*)sbuf)[i] = 0;

    // per-lane folded biases for the two owned column tiles
    const int nA = (2 * w) * 16 + m16, nB = (2 * w + 1) * 16 + m16;
    float bthh[2]  = {bias[BT_H + nA],    bias[BT_H + nB]};
    float btauh[2] = {bias[BTAU_H + nA],  bias[BTAU_H + nB]};
    float bht[2]   = {bias[BH_TOT + nA],  bias[BH_TOT + nB]};
    float btzr[2]  = {bias[BT_ZR + nA],   bias[BT_ZR + nB]};
    float btzi[2]  = {bias[BT_ZI + nA],   bias[BT_ZI + nB]};
    float btauz[2] = {bias[BTAU_Z + nA],  bias[BTAU_Z + nB]};
    float bzrt[2]  = {bias[BZR_TOT + nA], bias[BZR_TOT + nB]};
    float bzit[2]  = {bias[BZI_TOT + nA], bias[BZI_TOT + nB]};
    const int ny = w * 16 + m16;                   // y column for waves 0-3
    float by_ = (w < 4) ? bias[BY + ny] : 0.f;

    // fp32 state in C/D fragment layout: element (row hi*4+j, col (2w+u)*16+m16)
    float h_[2][4]  = {{0, 0, 0, 0}, {0, 0, 0, 0}};
    float zr_[2][4] = {{0, 0, 0, 0}, {0, 0, 0, 0}};
    float zi_[2][4] = {{0, 0, 0, 0}, {0, 0, 0, 0}};

    __syncthreads();

    for (int t = 0; t < T_; ++t) {
        const unsigned short (*cur)[4096] = sbuf[t & 1];
        unsigned short (*nxt)[4096]       = sbuf[(t + 1) & 1];

        // x fragments for this step, direct from global (used last -> latency hidden)
        const float* xrow = x + ((size_t)t * B_ + brow0 + m16) * INP_;
        bf16x8 ax[4];
#pragma unroll
        for (int kt = 0; kt < 4; ++kt) ax[kt] = loadXfrag(xrow, kt * 32 + hi * 8);

        // A-fragments: h and zr (reused by y-GEMM and the main GEMMs)
        bf16x8 ah[8], azr[8];
        loadA8(cur[0], m16, hi, ah);
        loadA8(cur[1], m16, hi, azr);

        // y_{t-1} from the CURRENT buffer's state (== h_n, zr_n of step t-1)
        if (w < 4 && t > 0) {
            f32x4 acc = {0.f, 0.f, 0.f, 0.f};
            gemmB<8, 8>(ah,  ws + OH, ny, hi, acc);
            gemmB<8, 8>(azr, ws + OZ, ny, hi, acc);
#pragma unroll
            for (int j = 0; j < 4; ++j)
                y[((size_t)(t - 1) * B_ + brow0 + hi * 4 + j) * OUT_ + ny] = acc[j] + by_;
        }

        // merged accumulators: ch = z2h + ux ; cz = h2z + uz
        f32x4 a_th[2], a_tau[2], a_cz[2], a_tzr[2], a_ch[2], a_tzi[2], a_tz[2];
#pragma unroll
        for (int u = 0; u < 2; ++u) {
            a_th[u] = a_tau[u] = a_cz[u] = a_tzr[u] = a_ch[u] = a_tzi[u] = a_tz[u]
                = (f32x4){0.f, 0.f, 0.f, 0.f};
        }
        const int nu[2] = {nA, nB};

#pragma unroll
        for (int u = 0; u < 2; ++u) {
            gemmB<8, 8>(ah, ws + WH,    nu[u], hi, a_th[u]);
            gemmB<8, 8>(ah, ws + WTAUH, nu[u], hi, a_tau[u]);
            gemmB<8, 8>(ah, ws + H2Z,   nu[u], hi, a_cz[u]);
        }
#pragma unroll
        for (int u = 0; u < 2; ++u) {
            gemmB<8, 8>(azr, ws + WZR, nu[u], hi, a_tzr[u]);
            gemmB<8, 8>(azr, ws + Z2H, nu[u], hi, a_ch[u]);
        }
        {
            bf16x8 azi[8];
            loadA8(cur[2], m16, hi, azi);
#pragma unroll
            for (int u = 0; u < 2; ++u) gemmB<8, 8>(azi, ws + WZI, nu[u], hi, a_tzi[u]);
        }
        {
            bf16x8 aza[8];
            loadA8(cur[3], m16, hi, aza);
#pragma unroll
            for (int u = 0; u < 2; ++u) gemmB<8, 8>(aza, ws + WTAUZ, nu[u], hi, a_tz[u]);
        }
#pragma unroll
        for (int u = 0; u < 2; ++u) {
            gemmB<4, 7>(ax, ws + UH, nu[u], hi, a_ch[u]);
            gemmB<4, 7>(ax, ws + UZ, nu[u], hi, a_cz[u]);
        }

        // epilogue + state writes (swizzled)
#pragma unroll
        for (int u = 0; u < 2; ++u) {
            const int n = nu[u];
#pragma unroll
            for (int j = 0; j < 4; ++j) {
                float th  = fminf(fmaxf(sigmoid_fast(a_tau[u][j] + btauh[u]), 0.01f), 1.0f) + 1e-6f;
                float dh  = -h_[u][j] + tanh_fast(a_th[u][j] + bthh[u]) + a_ch[u][j] + bht[u];
                float hn  = h_[u][j] + DT_ * dh * rcp_(th);
                float tz  = fminf(fmaxf(sigmoid_fast(a_tz[u][j] + btauz[u]), 0.01f), 1.0f) + 1e-6f;
                float rtz = rcp_(tz);
                float dzr = -zr_[u][j] + tanh_fast(a_tzr[u][j] + btzr[u]) + a_cz[u][j] + bzrt[u];
                float dzi = -zi_[u][j] + tanh_fast(a_tzi[u][j] + btzi[u]) + a_cz[u][j] + bzit[u];
                float zrn = zr_[u][j] + DT_ * dzr * rtz;
                float zin = zi_[u][j] + DT_ * dzi * rtz;
                float zan = sqrtf(zrn * zrn + zin * zin + 1e-24f);
                h_[u][j] = hn; zr_[u][j] = zrn; zi_[u][j] = zin;

                const int mr = hi * 4 + j;
                const int byte = (mr * 512 + n * 2) ^ ((mr & 7) << 4);
                *(unsigned short*)((char*)nxt[0] + byte) = f2bf(hn);
                *(unsigned short*)((char*)nxt[1] + byte) = f2bf(zrn);
                *(unsigned short*)((char*)nxt[2] + byte) = f2bf(zin);
                *(unsigned short*)((char*)nxt[3] + byte) = f2bf(zan);
            }
        }
        __syncthreads();   // new state visible; old buffer free for rewrite
    }

    // final output y_{T-1} from sbuf[0] (T_ even -> S_T lives in parity 0)
    if (w < 4) {
        bf16x8 ah[8], azr[8];
        loadA8(sbuf[0][0], m16, hi, ah);
        loadA8(sbuf[0][1], m16, hi, azr);
        f32x4 acc = {0.f, 0.f, 0.f, 0.f};
        gemmB<8, 8>(ah,  ws + OH, ny, hi, acc);
        gemmB<8, 8>(azr, ws + OZ, ny, hi, acc);
#pragma unroll
        for (int j = 0; j < 4; ++j)
            y[((size_t)(T_ - 1) * B_ + brow0 + hi * 4 + j) * OUT_ + ny] = acc[j] + by_;
    }
}

extern "C" void kernel_launch(void* const* d_in, const int* in_sizes, int n_in,
                              void* d_out, int out_size, void* d_ws, size_t ws_size,
                              hipStream_t stream) {
    const float* x = (const float*)d_in[0];
    unsigned short* ws = (unsigned short*)d_ws;
    float* bias = (float*)((char*)d_ws + BIAS_OFF_BYTES);

    prep_weights<<<(NW_TOTAL + 255) / 256, 256, 0, stream>>>(
        (const float*)d_in[1],  /* W_h_w */
        (const float*)d_in[5],  /* W_tau_h_w */
        (const float*)d_in[8],  /* W_z_real_w */
        (const float*)d_in[10], /* W_z_imag_w */
        (const float*)d_in[14], /* W_tau_z_w */
        (const float*)d_in[18], /* h2z_w */
        (const float*)d_in[20], /* z2h_w */
        (const float*)d_in[3],  /* U_h_w */
        (const float*)d_in[12], /* U_z_w */
        (const float*)d_in[22], /* out_h_w */
        (const float*)d_in[24], /* out_z_w */
        ws);
    prep_bias<<<1, 256, 0, stream>>>(
        (const float*)d_in[2],  /* W_h_b */
        (const float*)d_in[6],  /* W_tau_h_b */
        (const float*)d_in[4],  /* U_h_b */
        (const float*)d_in[7],  /* b_h */
        (const float*)d_in[21], /* z2h_b */
        (const float*)d_in[9],  /* W_z_real_b */
        (const float*)d_in[11], /* W_z_imag_b */
        (const float*)d_in[15], /* W_tau_z_b */
        (const float*)d_in[13], /* U_z_b */
        (const float*)d_in[16], /* b_z_real */
        (const float*)d_in[17], /* b_z_imag */
        (const float*)d_in[19], /* h2z_b */
        (const float*)d_in[23], /* out_h_b */
        (const float*)d_in[25], /* out_z_b */
        bias);
    twistor_main<<<16, 512, 0, stream>>>(x, ws, (float*)d_out);
}

// Round 3
// 14572.728 us; speedup vs baseline: 1.0320x; 1.0274x over previous
//
#include <hip/hip_runtime.h>
#include <hip/hip_bf16.h>
#include <math.h>

// ---------------- problem constants ----------------
#define T_    512
#define B_    256
#define INP_  128
#define HID_  256
#define OUT_  64
#define DT_   0.1f
#define CPL_  0.1f

typedef __attribute__((ext_vector_type(8))) short          bf16x8;
typedef __attribute__((ext_vector_type(4))) float          f32x4;
typedef __attribute__((ext_vector_type(4))) unsigned short u16x4;

// ---------------- ws layout (ushort units, FRAGMENT-PERMUTED) ----------------
// H region: 7 matrices (WH,WTAUH,WZR,WZI,WTAUZ,H2Z*CPL,Z2H*CPL), each 256x256.
//   ws[g*65536 + T*4096 + kt*512 + l*8 + j] = W_g[T*16 + (l&15)][kt*32 + (l>>4)*8 + j]
// U region: 2 matrices (UH, UZ), each 256x128, tile stride 2048.
// OUT region: 2 matrices (OH, OZ), each 64x256, tile stride 4096.
#define G_WH    0
#define G_WTAUH 1
#define G_WZR   2
#define G_WZI   3
#define G_WTAUZ 4
#define G_H2Z   5
#define G_Z2H   6
#define UH     458752   // 7*65536
#define UZ     491520
#define OH     524288
#define OZ     540672
#define NW_TOTAL 557056
#define BIAS_OFF_BYTES (NW_TOTAL * 2)
// bias arrays (float offsets within bias region)
#define BT_H    0     // tanh-arg bias for h path   (= W_h_b)
#define BTAU_H  256   // tau_h sigmoid-arg bias     (= W_tau_h_b)
#define BH_TOT  512   // U_h_b + b_h + CPL*z2h_b
#define BT_ZR   768   // = W_z_real_b
#define BT_ZI   1024  // = W_z_imag_b
#define BTAU_Z  1280  // = W_tau_z_b
#define BZR_TOT 1536  // U_z_b + b_z_real + CPL*h2z_b
#define BZI_TOT 1792  // U_z_b + b_z_imag + CPL*h2z_b
#define BY      2048  // out_h_b + out_z_b  (64)

// fp32 -> bf16, round-to-nearest-even
__device__ __forceinline__ unsigned short f2bf(float f) {
    unsigned int u = __float_as_uint(f);
    u += 0x7fffu + ((u >> 16) & 1u);
    return (unsigned short)(u >> 16);
}

__device__ __forceinline__ float rcp_(float x) { return __builtin_amdgcn_rcpf(x); }
__device__ __forceinline__ float sigmoid_fast(float x) {
    return rcp_(1.0f + __expf(-x));
}
__device__ __forceinline__ float tanh_fast(float x) {
    return 1.0f - 2.0f * rcp_(__expf(2.0f * x) + 1.0f);
}

// ---------------- prep: weights fp32 -> bf16, fragment-permuted ----------------
__global__ void prep_weights(const float* __restrict__ Wh,   const float* __restrict__ Wtauh,
                             const float* __restrict__ Wzr,  const float* __restrict__ Wzi,
                             const float* __restrict__ Wtauz,const float* __restrict__ h2z,
                             const float* __restrict__ z2h,  const float* __restrict__ Uh,
                             const float* __restrict__ Uz,   const float* __restrict__ oh,
                             const float* __restrict__ oz,   unsigned short* __restrict__ ws) {
    int fid = blockIdx.x * 256 + threadIdx.x;   // one 8-elem fragment per thread
    if (fid >= NW_TOTAL / 8) return;
    int o = fid * 8;
    const float* src;
    int row, col, K;
    float scale = 1.0f;
    if (o < UH) {                       // H region, K=256
        int g  = o >> 16;
        int r  = o & 65535;
        int T  = r >> 12;
        int r2 = r & 4095;
        int kt = r2 >> 9;
        int l  = (r2 & 511) >> 3;
        row = T * 16 + (l & 15);
        col = kt * 32 + (l >> 4) * 8;
        K = 256;
        if      (g == G_WH)    src = Wh;
        else if (g == G_WTAUH) src = Wtauh;
        else if (g == G_WZR)   src = Wzr;
        else if (g == G_WZI)   src = Wzi;
        else if (g == G_WTAUZ) src = Wtauz;
        else if (g == G_H2Z)   { src = h2z; scale = CPL_; }
        else                   { src = z2h; scale = CPL_; }
    } else if (o < OH) {                // U region, K=128
        int g  = (o - UH) >> 15;
        int r  = (o - UH) & 32767;
        int T  = r >> 11;
        int r2 = r & 2047;
        int kt = r2 >> 9;
        int l  = (r2 & 511) >> 3;
        row = T * 16 + (l & 15);
        col = kt * 32 + (l >> 4) * 8;
        K = 128;
        src = g ? Uz : Uh;
    } else {                            // OUT region, K=256
        int g  = (o - OH) >> 14;
        int r  = (o - OH) & 16383;
        int T  = r >> 12;
        int r2 = r & 4095;
        int kt = r2 >> 9;
        int l  = (r2 & 511) >> 3;
        row = T * 16 + (l & 15);
        col = kt * 32 + (l >> 4) * 8;
        K = 256;
        src = g ? oz : oh;
    }
    const float* p = src + (size_t)row * K + col;
    float4 v0 = *(const float4*)p;
    float4 v1 = *(const float4*)(p + 4);
    u16x4 a, b;
    a.x = f2bf(v0.x * scale); a.y = f2bf(v0.y * scale);
    a.z = f2bf(v0.z * scale); a.w = f2bf(v0.w * scale);
    b.x = f2bf(v1.x * scale); b.y = f2bf(v1.y * scale);
    b.z = f2bf(v1.z * scale); b.w = f2bf(v1.w * scale);
    *(u16x4*)(ws + o)     = a;
    *(u16x4*)(ws + o + 4) = b;
}

// ---------------- prep: folded biases (fp32) ----------------
__global__ void prep_bias(const float* __restrict__ Whb,  const float* __restrict__ Wtauhb,
                          const float* __restrict__ Uhb,  const float* __restrict__ bh,
                          const float* __restrict__ z2hb, const float* __restrict__ Wzrb,
                          const float* __restrict__ Wzib, const float* __restrict__ Wtauzb,
                          const float* __restrict__ Uzb,  const float* __restrict__ bzr,
                          const float* __restrict__ bzi,  const float* __restrict__ h2zb,
                          const float* __restrict__ ohb,  const float* __restrict__ ozb,
                          float* __restrict__ bias) {
    int n = threadIdx.x;
    if (n < 256) {
        bias[BT_H + n]    = Whb[n];
        bias[BTAU_H + n]  = Wtauhb[n];
        bias[BH_TOT + n]  = Uhb[n] + bh[n] + CPL_ * z2hb[n];
        bias[BT_ZR + n]   = Wzrb[n];
        bias[BT_ZI + n]   = Wzib[n];
        bias[BTAU_Z + n]  = Wtauzb[n];
        bias[BZR_TOT + n] = Uzb[n] + bzr[n] + CPL_ * h2zb[n];
        bias[BZI_TOT + n] = Uzb[n] + bzi[n] + CPL_ * h2zb[n];
        if (n < 64) bias[BY + n] = ohb[n] + ozb[n];
    }
}

// Load the 8 A-fragments (full K=256) for one state tile from swizzled LDS, once.
__device__ __forceinline__ void loadA8(const unsigned short* s, int m16, int hi, bf16x8* a) {
    const char* base = (const char*)s;
    const int xm = (m16 & 7) << 4;
#pragma unroll
    for (int kt = 0; kt < 8; ++kt)
        a[kt] = *(const bf16x8*)(base + ((m16 * 512 + kt * 64 + hi * 16) ^ xm));
}

// Dual-tile GEMM: A resident in regs, B fully coalesced (1KB/load) from L2.
template<int NKT>
__device__ __forceinline__ void gemm2(const bf16x8* a,
                                      const unsigned short* __restrict__ b0p,
                                      const unsigned short* __restrict__ b1p,
                                      int loff, f32x4& acc0, f32x4& acc1) {
    bf16x8 b0[NKT], b1[NKT];
#pragma unroll
    for (int kt = 0; kt < NKT; ++kt) b0[kt] = *(const bf16x8*)(b0p + kt * 512 + loff);
#pragma unroll
    for (int kt = 0; kt < NKT; ++kt) b1[kt] = *(const bf16x8*)(b1p + kt * 512 + loff);
#pragma unroll
    for (int kt = 0; kt < NKT; ++kt)
        acc0 = __builtin_amdgcn_mfma_f32_16x16x32_bf16(a[kt], b0[kt], acc0, 0, 0, 0);
#pragma unroll
    for (int kt = 0; kt < NKT; ++kt)
        acc1 = __builtin_amdgcn_mfma_f32_16x16x32_bf16(a[kt], b1[kt], acc1, 0, 0, 0);
}

// Single-tile GEMM (y output path)
template<int NKT>
__device__ __forceinline__ void gemm1(const bf16x8* a, const unsigned short* __restrict__ bp,
                                      int loff, f32x4& acc) {
    bf16x8 b[NKT];
#pragma unroll
    for (int kt = 0; kt < NKT; ++kt) b[kt] = *(const bf16x8*)(bp + kt * 512 + loff);
#pragma unroll
    for (int kt = 0; kt < NKT; ++kt)
        acc = __builtin_amdgcn_mfma_f32_16x16x32_bf16(a[kt], b[kt], acc, 0, 0, 0);
}

// x A-fragment straight from global fp32 (row = batch row, 8 consecutive cols)
__device__ __forceinline__ bf16x8 loadXfrag(const float* __restrict__ xrow, int off) {
    float4 v0 = *(const float4*)(xrow + off);
    float4 v1 = *(const float4*)(xrow + off + 4);
    bf16x8 r;
    r[0] = (short)f2bf(v0.x); r[1] = (short)f2bf(v0.y);
    r[2] = (short)f2bf(v0.z); r[3] = (short)f2bf(v0.w);
    r[4] = (short)f2bf(v1.x); r[5] = (short)f2bf(v1.y);
    r[6] = (short)f2bf(v1.z); r[7] = (short)f2bf(v1.w);
    return r;
}

// ---------------- main recurrent kernel ----------------
// grid: 16 blocks (16 batch rows each), 512 threads = 8 waves (2/SIMD).
// wave w owns column tiles {2w, 2w+1}; state double-buffered in LDS (1 barrier/step).
__launch_bounds__(512, 2)
__global__ void twistor_main(const float* __restrict__ x, const unsigned short* __restrict__ ws,
                             float* __restrict__ y) {
    // state buffers: [parity][state h,zr,zi,za][16 rows x 256 cols bf16, XOR-swizzled]
    __shared__ unsigned short sbuf[2][4][4096];   // 64 KiB

    const int tid  = threadIdx.x;
    const int lane = tid & 63;
    const int w    = tid >> 6;
    const int m16  = lane & 15;
    const int hi   = lane >> 4;
    const int loff = lane * 8;                     // fragment offset within a 1KB chunk
    const int brow0 = blockIdx.x * 16;
    const float* bias = (const float*)((const char*)ws + BIAS_OFF_BYTES);

    // per-wave fragment-layout weight bases (tiles 2w, 2w+1)
    const unsigned short* bWH0    = ws + G_WH    * 65536 + (2 * w) * 4096;
    const unsigned short* bWTAUH0 = ws + G_WTAUH * 65536 + (2 * w) * 4096;
    const unsigned short* bWZR0   = ws + G_WZR   * 65536 + (2 * w) * 4096;
    const unsigned short* bWZI0   = ws + G_WZI   * 65536 + (2 * w) * 4096;
    const unsigned short* bWTAUZ0 = ws + G_WTAUZ * 65536 + (2 * w) * 4096;
    const unsigned short* bH2Z0   = ws + G_H2Z   * 65536 + (2 * w) * 4096;
    const unsigned short* bZ2H0   = ws + G_Z2H   * 65536 + (2 * w) * 4096;
    const unsigned short* bUH0    = ws + UH + (2 * w) * 2048;
    const unsigned short* bUZ0    = ws + UZ + (2 * w) * 2048;
    const unsigned short* bOH     = ws + OH + w * 4096;   // waves 0..3 only
    const unsigned short* bOZ     = ws + OZ + w * 4096;

    // zero both state buffers
    for (int i = tid; i < 2 * 4 * 4096; i += 512) ((unsigned short*)sbuf)[i] = 0;

    // per-lane folded biases for the two owned column tiles
    const int nA = (2 * w) * 16 + m16, nB = (2 * w + 1) * 16 + m16;
    float bthh[2]  = {bias[BT_H + nA],    bias[BT_H + nB]};
    float btauh[2] = {bias[BTAU_H + nA],  bias[BTAU_H + nB]};
    float bht[2]   = {bias[BH_TOT + nA],  bias[BH_TOT + nB]};
    float btzr[2]  = {bias[BT_ZR + nA],   bias[BT_ZR + nB]};
    float btzi[2]  = {bias[BT_ZI + nA],   bias[BT_ZI + nB]};
    float btauz[2] = {bias[BTAU_Z + nA],  bias[BTAU_Z + nB]};
    float bzrt[2]  = {bias[BZR_TOT + nA], bias[BZR_TOT + nB]};
    float bzit[2]  = {bias[BZI_TOT + nA], bias[BZI_TOT + nB]};
    const int ny = w * 16 + m16;                   // y column for waves 0-3
    float by_ = (w < 4) ? bias[BY + ny] : 0.f;

    // fp32 state in C/D fragment layout: element (row hi*4+j, col (2w+u)*16+m16)
    float h_[2][4]  = {{0, 0, 0, 0}, {0, 0, 0, 0}};
    float zr_[2][4] = {{0, 0, 0, 0}, {0, 0, 0, 0}};
    float zi_[2][4] = {{0, 0, 0, 0}, {0, 0, 0, 0}};

    __syncthreads();

    for (int t = 0; t < T_; ++t) {
        const unsigned short (*cur)[4096] = sbuf[t & 1];
        unsigned short (*nxt)[4096]       = sbuf[(t + 1) & 1];

        // x fragments for this step, direct from global (used last -> latency hidden)
        const float* xrow = x + ((size_t)t * B_ + brow0 + m16) * INP_;
        bf16x8 ax[4];
#pragma unroll
        for (int kt = 0; kt < 4; ++kt) ax[kt] = loadXfrag(xrow, kt * 32 + hi * 8);

        // A-fragments: h and zr (reused by y-GEMM and the main GEMMs)
        bf16x8 ah[8], azr[8];
        loadA8(cur[0], m16, hi, ah);
        loadA8(cur[1], m16, hi, azr);

        // y_{t-1} from the CURRENT buffer's state (== h_n, zr_n of step t-1)
        if (w < 4 && t > 0) {
            f32x4 acc = {0.f, 0.f, 0.f, 0.f};
            gemm1<8>(ah,  bOH, loff, acc);
            gemm1<8>(azr, bOZ, loff, acc);
#pragma unroll
            for (int j = 0; j < 4; ++j)
                y[((size_t)(t - 1) * B_ + brow0 + hi * 4 + j) * OUT_ + ny] = acc[j] + by_;
        }

        // merged accumulators: ch = z2h + ux ; cz = h2z + uz
        f32x4 a_th[2], a_tau[2], a_cz[2], a_tzr[2], a_ch[2], a_tzi[2], a_tz[2];
#pragma unroll
        for (int u = 0; u < 2; ++u) {
            a_th[u] = a_tau[u] = a_cz[u] = a_tzr[u] = a_ch[u] = a_tzi[u] = a_tz[u]
                = (f32x4){0.f, 0.f, 0.f, 0.f};
        }

        gemm2<8>(ah, bWH0,    bWH0    + 4096, loff, a_th[0],  a_th[1]);
        gemm2<8>(ah, bWTAUH0, bWTAUH0 + 4096, loff, a_tau[0], a_tau[1]);
        gemm2<8>(ah, bH2Z0,   bH2Z0   + 4096, loff, a_cz[0],  a_cz[1]);
        gemm2<8>(azr, bWZR0,  bWZR0   + 4096, loff, a_tzr[0], a_tzr[1]);
        gemm2<8>(azr, bZ2H0,  bZ2H0   + 4096, loff, a_ch[0],  a_ch[1]);
        {
            bf16x8 azi[8];
            loadA8(cur[2], m16, hi, azi);
            gemm2<8>(azi, bWZI0, bWZI0 + 4096, loff, a_tzi[0], a_tzi[1]);
        }
        {
            bf16x8 aza[8];
            loadA8(cur[3], m16, hi, aza);
            gemm2<8>(aza, bWTAUZ0, bWTAUZ0 + 4096, loff, a_tz[0], a_tz[1]);
        }
        gemm2<4>(ax, bUH0, bUH0 + 2048, loff, a_ch[0], a_ch[1]);
        gemm2<4>(ax, bUZ0, bUZ0 + 2048, loff, a_cz[0], a_cz[1]);

        // epilogue + state writes (swizzled)
        const int nu[2] = {nA, nB};
#pragma unroll
        for (int u = 0; u < 2; ++u) {
            const int n = nu[u];
#pragma unroll
            for (int j = 0; j < 4; ++j) {
                float th  = fminf(fmaxf(sigmoid_fast(a_tau[u][j] + btauh[u]), 0.01f), 1.0f) + 1e-6f;
                float dh  = -h_[u][j] + tanh_fast(a_th[u][j] + bthh[u]) + a_ch[u][j] + bht[u];
                float hn  = h_[u][j] + DT_ * dh * rcp_(th);
                float tz  = fminf(fmaxf(sigmoid_fast(a_tz[u][j] + btauz[u]), 0.01f), 1.0f) + 1e-6f;
                float rtz = rcp_(tz);
                float dzr = -zr_[u][j] + tanh_fast(a_tzr[u][j] + btzr[u]) + a_cz[u][j] + bzrt[u];
                float dzi = -zi_[u][j] + tanh_fast(a_tzi[u][j] + btzi[u]) + a_cz[u][j] + bzit[u];
                float zrn = zr_[u][j] + DT_ * dzr * rtz;
                float zin = zi_[u][j] + DT_ * dzi * rtz;
                float zan = sqrtf(zrn * zrn + zin * zin + 1e-24f);
                h_[u][j] = hn; zr_[u][j] = zrn; zi_[u][j] = zin;

                const int mr = hi * 4 + j;
                const int byte = (mr * 512 + n * 2) ^ ((mr & 7) << 4);
                *(unsigned short*)((char*)nxt[0] + byte) = f2bf(hn);
                *(unsigned short*)((char*)nxt[1] + byte) = f2bf(zrn);
                *(unsigned short*)((char*)nxt[2] + byte) = f2bf(zin);
                *(unsigned short*)((char*)nxt[3] + byte) = f2bf(zan);
            }
        }
        __syncthreads();   // new state visible; old buffer free for rewrite
    }

    // final output y_{T-1} from sbuf[0] (T_ even -> S_T lives in parity 0)
    if (w < 4) {
        bf16x8 ah[8], azr[8];
        loadA8(sbuf[0][0], m16, hi, ah);
        loadA8(sbuf[0][1], m16, hi, azr);
        f32x4 acc = {0.f, 0.f, 0.f, 0.f};
        gemm1<8>(ah,  bOH, loff, acc);
        gemm1<8>(azr, bOZ, loff, acc);
#pragma unroll
        for (int j = 0; j < 4; ++j)
            y[((size_t)(T_ - 1) * B_ + brow0 + hi * 4 + j) * OUT_ + ny] = acc[j] + by_;
    }
}

extern "C" void kernel_launch(void* const* d_in, const int* in_sizes, int n_in,
                              void* d_out, int out_size, void* d_ws, size_t ws_size,
                              hipStream_t stream) {
    const float* x = (const float*)d_in[0];
    unsigned short* ws = (unsigned short*)d_ws;
    float* bias = (float*)((char*)d_ws + BIAS_OFF_BYTES);

    prep_weights<<<(NW_TOTAL / 8 + 255) / 256, 256, 0, stream>>>(
        (const float*)d_in[1],  /* W_h_w */
        (const float*)d_in[5],  /* W_tau_h_w */
        (const float*)d_in[8],  /* W_z_real_w */
        (const float*)d_in[10], /* W_z_imag_w */
        (const float*)d_in[14], /* W_tau_z_w */
        (const float*)d_in[18], /* h2z_w */
        (const float*)d_in[20], /* z2h_w */
        (const float*)d_in[3],  /* U_h_w */
        (const float*)d_in[12], /* U_z_w */
        (const float*)d_in[22], /* out_h_w */
        (const float*)d_in[24], /* out_z_w */
        ws);
    prep_bias<<<1, 256, 0, stream>>>(
        (const float*)d_in[2],  /* W_h_b */
        (const float*)d_in[6],  /* W_tau_h_b */
        (const float*)d_in[4],  /* U_h_b */
        (const float*)d_in[7],  /* b_h */
        (const float*)d_in[21], /* z2h_b */
        (const float*)d_in[9],  /* W_z_real_b */
        (const float*)d_in[11], /* W_z_imag_b */
        (const float*)d_in[15], /* W_tau_z_b */
        (const float*)d_in[13], /* U_z_b */
        (const float*)d_in[16], /* b_z_real */
        (const float*)d_in[17], /* b_z_imag */
        (const float*)d_in[19], /* h2z_b */
        (const float*)d_in[23], /* out_h_b */
        (const float*)d_in[25], /* out_z_b */
        bias);
    twistor_main<<<16, 512, 0, stream>>>(x, ws, (float*)d_out);
}

// Round 4
// 6101.114 us; speedup vs baseline: 2.4649x; 2.3885x over previous
//
#include <hip/hip_runtime.h>
#include <hip/hip_bf16.h>
#include <math.h>

// ---------------- problem constants ----------------
#define T_    512
#define B_    256
#define INP_  128
#define HID_  256
#define OUT_  64
#define DT_   0.1f
#define CPL_  0.1f

typedef __attribute__((ext_vector_type(8))) short          bf16x8;
typedef __attribute__((ext_vector_type(4))) float          f32x4;
typedef __attribute__((ext_vector_type(4))) unsigned short u16x4;

// ---------------- ws layout (ushort units, FRAGMENT-PERMUTED) ----------------
// H region: 7 matrices (WH,WTAUH,WZR,WZI,WTAUZ,H2Z*CPL,Z2H*CPL), each 256x256.
//   ws[g*65536 + T*4096 + kt*512 + l*8 + j] = W_g[T*16 + (l&15)][kt*32 + (l>>4)*8 + j]
// U region: 2 matrices (UH, UZ), each 256x128, tile stride 2048.
// OUT region: 2 matrices (OH, OZ), each 64x256, tile stride 4096.
#define G_WH    0
#define G_WTAUH 1
#define G_WZR   2
#define G_WZI   3
#define G_WTAUZ 4
#define G_H2Z   5
#define G_Z2H   6
#define UH     458752   // 7*65536
#define UZ     491520
#define OH     524288
#define OZ     540672
#define NW_TOTAL 557056
#define BIAS_OFF_BYTES (NW_TOTAL * 2)
// bias arrays (float offsets within bias region)
#define BT_H    0
#define BTAU_H  256
#define BH_TOT  512
#define BT_ZR   768
#define BT_ZI   1024
#define BTAU_Z  1280
#define BZR_TOT 1536
#define BZI_TOT 1792
#define BY      2048   // 64 floats
// after bias floats (2112 floats = 8448 bytes): barrier counters, then state buffers
#define CTR_OFF_BYTES   (BIAS_OFF_BYTES + 8448)   // 16 counters, 64B apart
#define STATE_OFF_BYTES (CTR_OFF_BYTES + 1024)
// state: u64 units, [parity2][rg16][state4][col256][q4]; q packs rows 4q..4q+3

// fp32 -> bf16, round-to-nearest-even
__device__ __forceinline__ unsigned short f2bf(float f) {
    unsigned int u = __float_as_uint(f);
    u += 0x7fffu + ((u >> 16) & 1u);
    return (unsigned short)(u >> 16);
}

__device__ __forceinline__ float rcp_(float x) { return __builtin_amdgcn_rcpf(x); }
__device__ __forceinline__ float sigmoid_fast(float x) {
    return rcp_(1.0f + __expf(-x));
}
__device__ __forceinline__ float tanh_fast(float x) {
    return 1.0f - 2.0f * rcp_(__expf(2.0f * x) + 1.0f);
}

// ---------------- prep: weights fp32 -> bf16, fragment-permuted ----------------
__global__ void prep_weights(const float* __restrict__ Wh,   const float* __restrict__ Wtauh,
                             const float* __restrict__ Wzr,  const float* __restrict__ Wzi,
                             const float* __restrict__ Wtauz,const float* __restrict__ h2z,
                             const float* __restrict__ z2h,  const float* __restrict__ Uh,
                             const float* __restrict__ Uz,   const float* __restrict__ oh,
                             const float* __restrict__ oz,   unsigned short* __restrict__ ws) {
    int fid = blockIdx.x * 256 + threadIdx.x;   // one 8-elem fragment per thread
    if (fid >= NW_TOTAL / 8) return;
    int o = fid * 8;
    const float* src;
    int row, col, K;
    float scale = 1.0f;
    if (o < UH) {                       // H region, K=256
        int g  = o >> 16;
        int r  = o & 65535;
        int T  = r >> 12;
        int r2 = r & 4095;
        int kt = r2 >> 9;
        int l  = (r2 & 511) >> 3;
        row = T * 16 + (l & 15);
        col = kt * 32 + (l >> 4) * 8;
        K = 256;
        if      (g == G_WH)    src = Wh;
        else if (g == G_WTAUH) src = Wtauh;
        else if (g == G_WZR)   src = Wzr;
        else if (g == G_WZI)   src = Wzi;
        else if (g == G_WTAUZ) src = Wtauz;
        else if (g == G_H2Z)   { src = h2z; scale = CPL_; }
        else                   { src = z2h; scale = CPL_; }
    } else if (o < OH) {                // U region, K=128
        int g  = (o - UH) >> 15;
        int r  = (o - UH) & 32767;
        int T  = r >> 11;
        int r2 = r & 2047;
        int kt = r2 >> 9;
        int l  = (r2 & 511) >> 3;
        row = T * 16 + (l & 15);
        col = kt * 32 + (l >> 4) * 8;
        K = 128;
        src = g ? Uz : Uh;
    } else {                            // OUT region, K=256
        int g  = (o - OH) >> 14;
        int r  = (o - OH) & 16383;
        int T  = r >> 12;
        int r2 = r & 4095;
        int kt = r2 >> 9;
        int l  = (r2 & 511) >> 3;
        row = T * 16 + (l & 15);
        col = kt * 32 + (l >> 4) * 8;
        K = 256;
        src = g ? oz : oh;
    }
    const float* p = src + (size_t)row * K + col;
    float4 v0 = *(const float4*)p;
    float4 v1 = *(const float4*)(p + 4);
    u16x4 a, b;
    a.x = f2bf(v0.x * scale); a.y = f2bf(v0.y * scale);
    a.z = f2bf(v0.z * scale); a.w = f2bf(v0.w * scale);
    b.x = f2bf(v1.x * scale); b.y = f2bf(v1.y * scale);
    b.z = f2bf(v1.z * scale); b.w = f2bf(v1.w * scale);
    *(u16x4*)(ws + o)     = a;
    *(u16x4*)(ws + o + 4) = b;
}

// ---------------- prep: folded biases (fp32) + zero barrier counters ----------------
__global__ void prep_bias(const float* __restrict__ Whb,  const float* __restrict__ Wtauhb,
                          const float* __restrict__ Uhb,  const float* __restrict__ bh,
                          const float* __restrict__ z2hb, const float* __restrict__ Wzrb,
                          const float* __restrict__ Wzib, const float* __restrict__ Wtauzb,
                          const float* __restrict__ Uzb,  const float* __restrict__ bzr,
                          const float* __restrict__ bzi,  const float* __restrict__ h2zb,
                          const float* __restrict__ ohb,  const float* __restrict__ ozb,
                          float* __restrict__ bias) {
    int n = threadIdx.x;
    if (n < 256) {
        bias[BT_H + n]    = Whb[n];
        bias[BTAU_H + n]  = Wtauhb[n];
        bias[BH_TOT + n]  = Uhb[n] + bh[n] + CPL_ * z2hb[n];
        bias[BT_ZR + n]   = Wzrb[n];
        bias[BT_ZI + n]   = Wzib[n];
        bias[BTAU_Z + n]  = Wtauzb[n];
        bias[BZR_TOT + n] = Uzb[n] + bzr[n] + CPL_ * h2zb[n];
        bias[BZI_TOT + n] = Uzb[n] + bzi[n] + CPL_ * h2zb[n];
        if (n < 64) bias[BY + n] = ohb[n] + ozb[n];
        if (n < 16) ((unsigned*)((char*)bias + 8448))[n * 16] = 0;  // barrier counters
    }
}

// Load the 8 A-fragments (full K=256) for one state tile from swizzled LDS.
__device__ __forceinline__ void loadA8(const unsigned short* s, int m16, int hi, bf16x8* a) {
    const char* base = (const char*)s;
    const int xm = (m16 & 7) << 4;
#pragma unroll
    for (int kt = 0; kt < 8; ++kt)
        a[kt] = *(const bf16x8*)(base + ((m16 * 512 + kt * 64 + hi * 16) ^ xm));
}

// Single-tile GEMM: A in regs, B fully coalesced (1KB/load) from L2.
template<int NKT>
__device__ __forceinline__ void gemm1(const bf16x8* a, const unsigned short* __restrict__ bp,
                                      int loff, f32x4& acc) {
    bf16x8 b[NKT];
#pragma unroll
    for (int kt = 0; kt < NKT; ++kt) b[kt] = *(const bf16x8*)(bp + kt * 512 + loff);
#pragma unroll
    for (int kt = 0; kt < NKT; ++kt)
        acc = __builtin_amdgcn_mfma_f32_16x16x32_bf16(a[kt], b[kt], acc, 0, 0, 0);
}

// x A-fragment straight from global fp32
__device__ __forceinline__ bf16x8 loadXfrag(const float* __restrict__ xrow, int off) {
    float4 v0 = *(const float4*)(xrow + off);
    float4 v1 = *(const float4*)(xrow + off + 4);
    bf16x8 r;
    r[0] = (short)f2bf(v0.x); r[1] = (short)f2bf(v0.y);
    r[2] = (short)f2bf(v0.z); r[3] = (short)f2bf(v0.w);
    r[4] = (short)f2bf(v1.x); r[5] = (short)f2bf(v1.y);
    r[6] = (short)f2bf(v1.z); r[7] = (short)f2bf(v1.w);
    return r;
}

__device__ __forceinline__ unsigned long long pack4(float a, float b, float c, float d) {
    unsigned lo = (unsigned)f2bf(a) | ((unsigned)f2bf(b) << 16);
    unsigned hi = (unsigned)f2bf(c) | ((unsigned)f2bf(d) << 16);
    return (unsigned long long)lo | ((unsigned long long)hi << 32);
}

// ---------------- main recurrent kernel ----------------
// grid: 32 blocks = 16 rowgroups x 2 colgroups. 512 threads = 8 waves,
// each wave owns ONE 16-col tile of its block's 128-col slice.
// Cross-block state exchange per step via agent-scope u64 atomics + rowgroup counter.
__launch_bounds__(512, 1)
__global__ void twistor_main(const float* __restrict__ x, unsigned short* __restrict__ ws,
                             float* __restrict__ y) {
    __shared__ unsigned short sst[4][4096];   // h, zr, zi, za  [16 rows x 256 cols], swizzled

    const int tid  = threadIdx.x;
    const int lane = tid & 63;
    const int w    = tid >> 6;          // 0..7
    const int m16  = lane & 15;
    const int hi   = lane >> 4;
    const int loff = lane * 8;
    const int bid  = blockIdx.x;
    const int rg   = bid >> 1;          // rowgroup 0..15
    const int cg   = bid & 1;           // colgroup 0..1
    const int brow0 = rg * 16;
    const float* bias = (const float*)((const char*)ws + BIAS_OFF_BYTES);
    unsigned* ctr = (unsigned*)((char*)ws + CTR_OFF_BYTES) + rg * 16;
    unsigned long long* sb = (unsigned long long*)((char*)ws + STATE_OFF_BYTES);

    const int tt = cg * 8 + w;          // this wave's col tile 0..15
    const int n  = tt * 16 + m16;       // this lane's output col

    const unsigned short* bWH    = ws + G_WH    * 65536 + tt * 4096;
    const unsigned short* bWTAUH = ws + G_WTAUH * 65536 + tt * 4096;
    const unsigned short* bWZR   = ws + G_WZR   * 65536 + tt * 4096;
    const unsigned short* bWZI   = ws + G_WZI   * 65536 + tt * 4096;
    const unsigned short* bWTAUZ = ws + G_WTAUZ * 65536 + tt * 4096;
    const unsigned short* bH2Z   = ws + G_H2Z   * 65536 + tt * 4096;
    const unsigned short* bZ2H   = ws + G_Z2H   * 65536 + tt * 4096;
    const unsigned short* bUHp   = ws + UH + tt * 2048;
    const unsigned short* bUZp   = ws + UZ + tt * 2048;
    // y duty: waves 0,1 handle y tiles 2*cg+w
    const bool ydo = (w < 2);
    const int ty = 2 * cg + w;
    const unsigned short* bOHp = ws + OH + ty * 4096;
    const unsigned short* bOZp = ws + OZ + ty * 4096;
    const int ny = ty * 16 + m16;
    float by_ = ydo ? bias[BY + ny] : 0.f;

    const float bthh  = bias[BT_H + n],    btauh = bias[BTAU_H + n];
    const float bht   = bias[BH_TOT + n],  btzr  = bias[BT_ZR + n];
    const float btzi  = bias[BT_ZI + n],   btauz = bias[BTAU_Z + n];
    const float bzrt  = bias[BZR_TOT + n], bzit  = bias[BZI_TOT + n];

    float h_[4]  = {0, 0, 0, 0};
    float zr_[4] = {0, 0, 0, 0};
    float zi_[4] = {0, 0, 0, 0};

    for (int i = tid; i < 4 * 4096; i += 512) ((unsigned short*)sst)[i] = 0;
    __syncthreads();

    const int rsIdx = tid >> 7;          // read-phase state index 0..3
    const int rn0   = (tid & 127) * 2;   // read-phase col base (2 cols/thread)

    for (int t = 0; t < T_; ++t) {
        const int p = (t + 1) & 1;

        // x fragments (global fp32 -> bf16 regs)
        const float* xrow = x + ((size_t)t * B_ + brow0 + m16) * INP_;
        bf16x8 ax[4];
#pragma unroll
        for (int kt = 0; kt < 4; ++kt) ax[kt] = loadXfrag(xrow, kt * 32 + hi * 8);

        bf16x8 ah[8], azr[8];
        loadA8(sst[0], m16, hi, ah);
        loadA8(sst[1], m16, hi, azr);

        // y_{t-1} from current staged state (== S_t)
        if (ydo && t > 0) {
            f32x4 acc = {0.f, 0.f, 0.f, 0.f};
            gemm1<8>(ah,  bOHp, loff, acc);
            gemm1<8>(azr, bOZp, loff, acc);
#pragma unroll
            for (int j = 0; j < 4; ++j)
                y[((size_t)(t - 1) * B_ + brow0 + hi * 4 + j) * OUT_ + ny] = acc[j] + by_;
        }

        f32x4 a_th  = {0.f, 0.f, 0.f, 0.f}, a_tau = {0.f, 0.f, 0.f, 0.f};
        f32x4 a_cz  = {0.f, 0.f, 0.f, 0.f}, a_tzr = {0.f, 0.f, 0.f, 0.f};
        f32x4 a_ch  = {0.f, 0.f, 0.f, 0.f}, a_tzi = {0.f, 0.f, 0.f, 0.f};
        f32x4 a_tz  = {0.f, 0.f, 0.f, 0.f};

        gemm1<8>(ah,  bWH,    loff, a_th);
        gemm1<8>(ah,  bWTAUH, loff, a_tau);
        gemm1<8>(ah,  bH2Z,   loff, a_cz);
        gemm1<8>(azr, bWZR,   loff, a_tzr);
        gemm1<8>(azr, bZ2H,   loff, a_ch);
        {
            bf16x8 azi[8];
            loadA8(sst[2], m16, hi, azi);
            gemm1<8>(azi, bWZI, loff, a_tzi);
        }
        {
            bf16x8 aza[8];
            loadA8(sst[3], m16, hi, aza);
            gemm1<8>(aza, bWTAUZ, loff, a_tz);
        }
        gemm1<4>(ax, bUHp, loff, a_ch);
        gemm1<4>(ax, bUZp, loff, a_cz);

        // epilogue (one tile)
        float hn[4], zrn[4], zin[4], zan[4];
#pragma unroll
        for (int j = 0; j < 4; ++j) {
            float th  = fminf(fmaxf(sigmoid_fast(a_tau[j] + btauh), 0.01f), 1.0f) + 1e-6f;
            float dh  = -h_[j] + tanh_fast(a_th[j] + bthh) + a_ch[j] + bht;
            hn[j]     = h_[j] + DT_ * dh * rcp_(th);
            float tz  = fminf(fmaxf(sigmoid_fast(a_tz[j] + btauz), 0.01f), 1.0f) + 1e-6f;
            float rtz = rcp_(tz);
            float dzr = -zr_[j] + tanh_fast(a_tzr[j] + btzr) + a_cz[j] + bzrt;
            float dzi = -zi_[j] + tanh_fast(a_tzi[j] + btzi) + a_cz[j] + bzit;
            zrn[j] = zr_[j] + DT_ * dzr * rtz;
            zin[j] = zi_[j] + DT_ * dzi * rtz;
            zan[j] = sqrtf(zrn[j] * zrn[j] + zin[j] * zin[j] + 1e-24f);
            h_[j] = hn[j]; zr_[j] = zrn[j]; zi_[j] = zin[j];
        }

        // publish own slice: [p][rg][s][col n][q=hi] packs rows 4hi..4hi+3
        {
            size_t base = (((size_t)p * 16 + rg) * 4) * 1024 + (size_t)n * 4 + hi;
            __hip_atomic_store(&sb[base],        pack4(hn[0],  hn[1],  hn[2],  hn[3]),
                               __ATOMIC_RELAXED, __HIP_MEMORY_SCOPE_AGENT);
            __hip_atomic_store(&sb[base + 1024], pack4(zrn[0], zrn[1], zrn[2], zrn[3]),
                               __ATOMIC_RELAXED, __HIP_MEMORY_SCOPE_AGENT);
            __hip_atomic_store(&sb[base + 2048], pack4(zin[0], zin[1], zin[2], zin[3]),
                               __ATOMIC_RELAXED, __HIP_MEMORY_SCOPE_AGENT);
            __hip_atomic_store(&sb[base + 3072], pack4(zan[0], zan[1], zan[2], zan[3]),
                               __ATOMIC_RELAXED, __HIP_MEMORY_SCOPE_AGENT);
        }
        __syncthreads();   // all LDS reads done; all agent stores drained (vmcnt 0)

        if (tid == 0) {
            __hip_atomic_fetch_add(ctr, 1u, __ATOMIC_RELAXED, __HIP_MEMORY_SCOPE_AGENT);
            const unsigned tgt = 2u * (unsigned)(t + 1);
            while (__hip_atomic_load(ctr, __ATOMIC_RELAXED, __HIP_MEMORY_SCOPE_AGENT) < tgt)
                __builtin_amdgcn_s_sleep(2);
        }
        __syncthreads();   // peers published; safe to overwrite sst

        // read full rowgroup state -> LDS (thread: state rsIdx, cols rn0, rn0+1)
        {
            const size_t rb = (((size_t)p * 16 + rg) * 4 + rsIdx) * 1024;
            unsigned long long vb[8];
#pragma unroll
            for (int dn = 0; dn < 2; ++dn)
#pragma unroll
                for (int q = 0; q < 4; ++q)
                    vb[dn * 4 + q] = __hip_atomic_load(&sb[rb + (size_t)(rn0 + dn) * 4 + q],
                                                       __ATOMIC_RELAXED, __HIP_MEMORY_SCOPE_AGENT);
            char* sbase = (char*)sst[rsIdx];
#pragma unroll
            for (int dn = 0; dn < 2; ++dn) {
                const int nc = rn0 + dn;
#pragma unroll
                for (int q = 0; q < 4; ++q) {
                    const unsigned long long v = vb[dn * 4 + q];
#pragma unroll
                    for (int e = 0; e < 4; ++e) {
                        const int r = q * 4 + e;
                        *(unsigned short*)(sbase + ((r * 512 + nc * 2) ^ ((r & 7) << 4))) =
                            (unsigned short)(v >> (e * 16));
                    }
                }
            }
        }
        __syncthreads();   // sst ready for next step
    }

    // final y_{T-1} from S_T (staged in sst by last exchange)
    if (ydo) {
        bf16x8 ah[8], azr[8];
        loadA8(sst[0], m16, hi, ah);
        loadA8(sst[1], m16, hi, azr);
        f32x4 acc = {0.f, 0.f, 0.f, 0.f};
        gemm1<8>(ah,  bOHp, loff, acc);
        gemm1<8>(azr, bOZp, loff, acc);
#pragma unroll
        for (int j = 0; j < 4; ++j)
            y[((size_t)(T_ - 1) * B_ + brow0 + hi * 4 + j) * OUT_ + ny] = acc[j] + by_;
    }
}

extern "C" void kernel_launch(void* const* d_in, const int* in_sizes, int n_in,
                              void* d_out, int out_size, void* d_ws, size_t ws_size,
                              hipStream_t stream) {
    const float* x = (const float*)d_in[0];
    unsigned short* ws = (unsigned short*)d_ws;
    float* bias = (float*)((char*)d_ws + BIAS_OFF_BYTES);

    prep_weights<<<(NW_TOTAL / 8 + 255) / 256, 256, 0, stream>>>(
        (const float*)d_in[1],  /* W_h_w */
        (const float*)d_in[5],  /* W_tau_h_w */
        (const float*)d_in[8],  /* W_z_real_w */
        (const float*)d_in[10], /* W_z_imag_w */
        (const float*)d_in[14], /* W_tau_z_w */
        (const float*)d_in[18], /* h2z_w */
        (const float*)d_in[20], /* z2h_w */
        (const float*)d_in[3],  /* U_h_w */
        (const float*)d_in[12], /* U_z_w */
        (const float*)d_in[22], /* out_h_w */
        (const float*)d_in[24], /* out_z_w */
        ws);
    prep_bias<<<1, 256, 0, stream>>>(
        (const float*)d_in[2],  /* W_h_b */
        (const float*)d_in[6],  /* W_tau_h_b */
        (const float*)d_in[4],  /* U_h_b */
        (const float*)d_in[7],  /* b_h */
        (const float*)d_in[21], /* z2h_b */
        (const float*)d_in[9],  /* W_z_real_b */
        (const float*)d_in[11], /* W_z_imag_b */
        (const float*)d_in[15], /* W_tau_z_b */
        (const float*)d_in[13], /* U_z_b */
        (const float*)d_in[16], /* b_z_real */
        (const float*)d_in[17], /* b_z_imag */
        (const float*)d_in[19], /* h2z_b */
        (const float*)d_in[23], /* out_h_b */
        (const float*)d_in[25], /* out_z_b */
        bias);
    twistor_main<<<32, 512, 0, stream>>>(x, ws, (float*)d_out);
}

// Round 5
// 4466.517 us; speedup vs baseline: 3.3670x; 1.3660x over previous
//
#include <hip/hip_runtime.h>
#include <hip/hip_bf16.h>
#include <math.h>

// ---------------- problem constants ----------------
#define T_    512
#define B_    256
#define INP_  128
#define HID_  256
#define OUT_  64
#define DT_   0.1f
#define CPL_  0.1f

typedef __attribute__((ext_vector_type(8))) short          bf16x8;
typedef __attribute__((ext_vector_type(4))) float          f32x4;
typedef __attribute__((ext_vector_type(4))) unsigned short u16x4;

// ---------------- ws layout (ushort units, FRAGMENT-PERMUTED) ----------------
// H region: 7 matrices (WH,WTAUH,WZR,WZI,WTAUZ,H2Z*CPL,Z2H*CPL), each 256x256.
//   ws[g*65536 + T*4096 + kt*512 + l*8 + j] = W_g[T*16 + (l&15)][kt*32 + (l>>4)*8 + j]
// U region: 2 matrices (UH, UZ), each 256x128, tile stride 2048.
// OUT region: 2 matrices (OH, OZ), each 64x256, tile stride 4096.
#define G_WH    0
#define G_WTAUH 1
#define G_WZR   2
#define G_WZI   3
#define G_WTAUZ 4
#define G_H2Z   5
#define G_Z2H   6
#define UH     458752   // 7*65536
#define UZ     491520
#define OH     524288
#define OZ     540672
#define NW_TOTAL 557056
#define BIAS_OFF_BYTES (NW_TOTAL * 2)
// bias arrays (float offsets within bias region)
#define BT_H    0
#define BTAU_H  256
#define BH_TOT  512
#define BT_ZR   768
#define BT_ZI   1024
#define BTAU_Z  1280
#define BZR_TOT 1536
#define BZI_TOT 1792
#define BY      2048   // 64 floats
// after bias floats (2112 floats = 8448 bytes): barrier counters, then state buffers
#define CTR_OFF_BYTES   (BIAS_OFF_BYTES + 8448)   // 16 counters, 64B apart
#define STATE_OFF_BYTES (CTR_OFF_BYTES + 1024)
// state: u64 units, [parity2][rg16][state4][col256][q4]; q packs rows 4q..4q+3

// fp32 -> bf16, round-to-nearest-even
__device__ __forceinline__ unsigned short f2bf(float f) {
    unsigned int u = __float_as_uint(f);
    u += 0x7fffu + ((u >> 16) & 1u);
    return (unsigned short)(u >> 16);
}

__device__ __forceinline__ float rcp_(float x) { return __builtin_amdgcn_rcpf(x); }
__device__ __forceinline__ float sigmoid_fast(float x) {
    return rcp_(1.0f + __expf(-x));
}
__device__ __forceinline__ float tanh_fast(float x) {
    return 1.0f - 2.0f * rcp_(__expf(2.0f * x) + 1.0f);
}

// ---------------- prep: weights fp32 -> bf16, fragment-permuted ----------------
__global__ void prep_weights(const float* __restrict__ Wh,   const float* __restrict__ Wtauh,
                             const float* __restrict__ Wzr,  const float* __restrict__ Wzi,
                             const float* __restrict__ Wtauz,const float* __restrict__ h2z,
                             const float* __restrict__ z2h,  const float* __restrict__ Uh,
                             const float* __restrict__ Uz,   const float* __restrict__ oh,
                             const float* __restrict__ oz,   unsigned short* __restrict__ ws) {
    int fid = blockIdx.x * 256 + threadIdx.x;   // one 8-elem fragment per thread
    if (fid >= NW_TOTAL / 8) return;
    int o = fid * 8;
    const float* src;
    int row, col, K;
    float scale = 1.0f;
    if (o < UH) {                       // H region, K=256
        int g  = o >> 16;
        int r  = o & 65535;
        int T  = r >> 12;
        int r2 = r & 4095;
        int kt = r2 >> 9;
        int l  = (r2 & 511) >> 3;
        row = T * 16 + (l & 15);
        col = kt * 32 + (l >> 4) * 8;
        K = 256;
        if      (g == G_WH)    src = Wh;
        else if (g == G_WTAUH) src = Wtauh;
        else if (g == G_WZR)   src = Wzr;
        else if (g == G_WZI)   src = Wzi;
        else if (g == G_WTAUZ) src = Wtauz;
        else if (g == G_H2Z)   { src = h2z; scale = CPL_; }
        else                   { src = z2h; scale = CPL_; }
    } else if (o < OH) {                // U region, K=128
        int g  = (o - UH) >> 15;
        int r  = (o - UH) & 32767;
        int T  = r >> 11;
        int r2 = r & 2047;
        int kt = r2 >> 9;
        int l  = (r2 & 511) >> 3;
        row = T * 16 + (l & 15);
        col = kt * 32 + (l >> 4) * 8;
        K = 128;
        src = g ? Uz : Uh;
    } else {                            // OUT region, K=256
        int g  = (o - OH) >> 14;
        int r  = (o - OH) & 16383;
        int T  = r >> 12;
        int r2 = r & 4095;
        int kt = r2 >> 9;
        int l  = (r2 & 511) >> 3;
        row = T * 16 + (l & 15);
        col = kt * 32 + (l >> 4) * 8;
        K = 256;
        src = g ? oz : oh;
    }
    const float* p = src + (size_t)row * K + col;
    float4 v0 = *(const float4*)p;
    float4 v1 = *(const float4*)(p + 4);
    u16x4 a, b;
    a.x = f2bf(v0.x * scale); a.y = f2bf(v0.y * scale);
    a.z = f2bf(v0.z * scale); a.w = f2bf(v0.w * scale);
    b.x = f2bf(v1.x * scale); b.y = f2bf(v1.y * scale);
    b.z = f2bf(v1.z * scale); b.w = f2bf(v1.w * scale);
    *(u16x4*)(ws + o)     = a;
    *(u16x4*)(ws + o + 4) = b;
}

// ---------------- prep: folded biases (fp32) + zero barrier counters ----------------
__global__ void prep_bias(const float* __restrict__ Whb,  const float* __restrict__ Wtauhb,
                          const float* __restrict__ Uhb,  const float* __restrict__ bh,
                          const float* __restrict__ z2hb, const float* __restrict__ Wzrb,
                          const float* __restrict__ Wzib, const float* __restrict__ Wtauzb,
                          const float* __restrict__ Uzb,  const float* __restrict__ bzr,
                          const float* __restrict__ bzi,  const float* __restrict__ h2zb,
                          const float* __restrict__ ohb,  const float* __restrict__ ozb,
                          float* __restrict__ bias) {
    int n = threadIdx.x;
    if (n < 256) {
        bias[BT_H + n]    = Whb[n];
        bias[BTAU_H + n]  = Wtauhb[n];
        bias[BH_TOT + n]  = Uhb[n] + bh[n] + CPL_ * z2hb[n];
        bias[BT_ZR + n]   = Wzrb[n];
        bias[BT_ZI + n]   = Wzib[n];
        bias[BTAU_Z + n]  = Wtauzb[n];
        bias[BZR_TOT + n] = Uzb[n] + bzr[n] + CPL_ * h2zb[n];
        bias[BZI_TOT + n] = Uzb[n] + bzi[n] + CPL_ * h2zb[n];
        if (n < 64) bias[BY + n] = ohb[n] + ozb[n];
        if (n < 16) ((unsigned*)((char*)bias + 8448))[n * 16] = 0;  // barrier counters
    }
}

// Load the 8 A-fragments (full K=256) for one state tile from swizzled LDS.
__device__ __forceinline__ void loadA8(const unsigned short* s, int m16, int hi, bf16x8* a) {
    const char* base = (const char*)s;
    const int xm = (m16 & 7) << 4;
#pragma unroll
    for (int kt = 0; kt < 8; ++kt)
        a[kt] = *(const bf16x8*)(base + ((m16 * 512 + kt * 64 + hi * 16) ^ xm));
}

// Single-matrix GEMM: A in regs, B fully coalesced (1KB/load) from L2.
template<int NKT>
__device__ __forceinline__ void gemm1(const bf16x8* a, const unsigned short* __restrict__ bp,
                                      int loff, f32x4& acc) {
    bf16x8 b[NKT];
#pragma unroll
    for (int kt = 0; kt < NKT; ++kt) b[kt] = *(const bf16x8*)(bp + kt * 512 + loff);
#pragma unroll
    for (int kt = 0; kt < NKT; ++kt)
        acc = __builtin_amdgcn_mfma_f32_16x16x32_bf16(a[kt], b[kt], acc, 0, 0, 0);
}

// Fused 2-matrix GEMM (possibly different A operands): all loads issued first (MLP).
template<int NKT0, int NKT1>
__device__ __forceinline__ void gemm2m(const bf16x8* a0, const unsigned short* __restrict__ b0p,
                                       const bf16x8* a1, const unsigned short* __restrict__ b1p,
                                       int loff, f32x4& acc0, f32x4& acc1) {
    bf16x8 b0[NKT0], b1[NKT1];
#pragma unroll
    for (int kt = 0; kt < NKT0; ++kt) b0[kt] = *(const bf16x8*)(b0p + kt * 512 + loff);
#pragma unroll
    for (int kt = 0; kt < NKT1; ++kt) b1[kt] = *(const bf16x8*)(b1p + kt * 512 + loff);
#pragma unroll
    for (int kt = 0; kt < NKT0; ++kt)
        acc0 = __builtin_amdgcn_mfma_f32_16x16x32_bf16(a0[kt], b0[kt], acc0, 0, 0, 0);
#pragma unroll
    for (int kt = 0; kt < NKT1; ++kt)
        acc1 = __builtin_amdgcn_mfma_f32_16x16x32_bf16(a1[kt], b1[kt], acc1, 0, 0, 0);
}

// x A-fragment straight from global fp32
__device__ __forceinline__ bf16x8 loadXfrag(const float* __restrict__ xrow, int off) {
    float4 v0 = *(const float4*)(xrow + off);
    float4 v1 = *(const float4*)(xrow + off + 4);
    bf16x8 r;
    r[0] = (short)f2bf(v0.x); r[1] = (short)f2bf(v0.y);
    r[2] = (short)f2bf(v0.z); r[3] = (short)f2bf(v0.w);
    r[4] = (short)f2bf(v1.x); r[5] = (short)f2bf(v1.y);
    r[6] = (short)f2bf(v1.z); r[7] = (short)f2bf(v1.w);
    return r;
}

__device__ __forceinline__ unsigned long long pack4(float a, float b, float c, float d) {
    unsigned lo = (unsigned)f2bf(a) | ((unsigned)f2bf(b) << 16);
    unsigned hi = (unsigned)f2bf(c) | ((unsigned)f2bf(d) << 16);
    return (unsigned long long)lo | ((unsigned long long)hi << 32);
}

// ---------------- main recurrent kernel ----------------
// grid: 64 blocks = 16 rowgroups x 4 colgroups. 512 threads = 8 waves = 4 pairs.
// Pair p owns col tile cg*4+p; within a pair: h-wave (w&1==0) computes the h-path,
// z-wave (w&1==1) the z-path (disjoint epilogues -> no acc exchange).
// Cross-block state exchange per step via agent-scope u64 atomics + rowgroup counter.
__launch_bounds__(512, 1)
__global__ void twistor_main(const float* __restrict__ x, unsigned short* __restrict__ ws,
                             float* __restrict__ y) {
    __shared__ unsigned short sst[4][4096];   // h, zr, zi, za  [16 rows x 256 cols], swizzled
    __shared__ float yslot[64][4];            // OZ partial from wave 2 -> wave 0

    const int tid  = threadIdx.x;
    const int lane = tid & 63;
    const int w    = tid >> 6;          // 0..7
    const int pair = w >> 1;            // 0..3
    const int role = w & 1;             // 0 = h-wave, 1 = z-wave
    const int m16  = lane & 15;
    const int hi   = lane >> 4;
    const int loff = lane * 8;
    const int bid  = blockIdx.x;
    const int rg   = bid >> 2;          // rowgroup 0..15
    const int cg   = bid & 3;           // colgroup 0..3
    const int brow0 = rg * 16;
    const float* bias = (const float*)((const char*)ws + BIAS_OFF_BYTES);
    unsigned* ctr = (unsigned*)((char*)ws + CTR_OFF_BYTES) + rg * 16;
    unsigned long long* sb = (unsigned long long*)((char*)ws + STATE_OFF_BYTES);

    const int tt = cg * 4 + pair;       // this pair's col tile 0..15
    const int n  = tt * 16 + m16;       // this lane's output col

    const unsigned short* bWH    = ws + G_WH    * 65536 + tt * 4096;
    const unsigned short* bWTAUH = ws + G_WTAUH * 65536 + tt * 4096;
    const unsigned short* bWZR   = ws + G_WZR   * 65536 + tt * 4096;
    const unsigned short* bWZI   = ws + G_WZI   * 65536 + tt * 4096;
    const unsigned short* bWTAUZ = ws + G_WTAUZ * 65536 + tt * 4096;
    const unsigned short* bH2Z   = ws + G_H2Z   * 65536 + tt * 4096;
    const unsigned short* bZ2H   = ws + G_Z2H   * 65536 + tt * 4096;
    const unsigned short* bUHp   = ws + UH + tt * 2048;
    const unsigned short* bUZp   = ws + UZ + tt * 2048;
    // y duty: colgroup cg handles y-tile cg. wave 0: OH partial; wave 2: OZ partial.
    const unsigned short* bOHp = ws + OH + cg * 4096;
    const unsigned short* bOZp = ws + OZ + cg * 4096;
    const int ny = cg * 16 + m16;
    const float by_ = (w == 0) ? bias[BY + ny] : 0.f;

    // per-lane biases (role-relevant only)
    const float bthh  = bias[BT_H + n],    btauh = bias[BTAU_H + n];
    const float bht   = bias[BH_TOT + n],  btzr  = bias[BT_ZR + n];
    const float btzi  = bias[BT_ZI + n],   btauz = bias[BTAU_Z + n];
    const float bzrt  = bias[BZR_TOT + n], bzit  = bias[BZI_TOT + n];

    float h_[4]  = {0, 0, 0, 0};        // h-wave state
    float zr_[4] = {0, 0, 0, 0};        // z-wave state
    float zi_[4] = {0, 0, 0, 0};

    for (int i = tid; i < 4 * 4096; i += 512) ((unsigned short*)sst)[i] = 0;
    __syncthreads();

    const int rsIdx = tid >> 7;          // read-phase state index 0..3
    const int rn0   = (tid & 127) * 2;   // read-phase col base (2 cols/thread)

    // x fragments for t=0
    bf16x8 ax[4];
    {
        const float* xrow = x + ((size_t)brow0 + m16) * INP_;
#pragma unroll
        for (int kt = 0; kt < 4; ++kt) ax[kt] = loadXfrag(xrow, kt * 32 + hi * 8);
    }

    for (int t = 0; t < T_; ++t) {
        const int p = (t + 1) & 1;

        // A-fragments (shared by y-GEMM and main GEMMs)
        bf16x8 ah[8], azr[8];
        loadA8(sst[0], m16, hi, ah);
        loadA8(sst[1], m16, hi, azr);

        // y partials for y_{t-1} (sst == S_t)
        f32x4 a_y = {0.f, 0.f, 0.f, 0.f};
        if (t > 0) {
            if (w == 0) gemm1<8>(ah, bOHp, loff, a_y);
            if (w == 2) {
                gemm1<8>(azr, bOZp, loff, a_y);
                *(f32x4*)yslot[lane] = a_y;
            }
        }

        if (role == 0) {
            // ---- h-path: WH, WTAUH (A=ah), Z2H (A=azr), UH (A=ax) ----
            f32x4 a_th = {0.f, 0.f, 0.f, 0.f}, a_tau = {0.f, 0.f, 0.f, 0.f};
            f32x4 a_ch = {0.f, 0.f, 0.f, 0.f};
            gemm2m<8, 8>(ah, bWH, ah, bWTAUH, loff, a_th, a_tau);
            gemm2m<8, 4>(azr, bZ2H, ax, bUHp, loff, a_ch, a_ch);
            float hn[4];
#pragma unroll
            for (int j = 0; j < 4; ++j) {
                float th = fminf(fmaxf(sigmoid_fast(a_tau[j] + btauh), 0.01f), 1.0f) + 1e-6f;
                float dh = -h_[j] + tanh_fast(a_th[j] + bthh) + a_ch[j] + bht;
                hn[j]    = h_[j] + DT_ * dh * rcp_(th);
                h_[j] = hn[j];
            }
            size_t base = (((size_t)p * 16 + rg) * 4) * 1024 + (size_t)n * 4 + hi;
            __hip_atomic_store(&sb[base], pack4(hn[0], hn[1], hn[2], hn[3]),
                               __ATOMIC_RELAXED, __HIP_MEMORY_SCOPE_AGENT);
        } else {
            // ---- z-path: WZR (azr), WZI (azi), WTAUZ (aza), H2Z (ah), UZ (ax) ----
            f32x4 a_tzr = {0.f, 0.f, 0.f, 0.f}, a_tzi = {0.f, 0.f, 0.f, 0.f};
            f32x4 a_tz  = {0.f, 0.f, 0.f, 0.f}, a_cz  = {0.f, 0.f, 0.f, 0.f};
            {
                bf16x8 azi[8];
                loadA8(sst[2], m16, hi, azi);
                gemm2m<8, 8>(azr, bWZR, azi, bWZI, loff, a_tzr, a_tzi);
            }
            {
                bf16x8 aza[8];
                loadA8(sst[3], m16, hi, aza);
                gemm2m<8, 8>(aza, bWTAUZ, ah, bH2Z, loff, a_tz, a_cz);
            }
            gemm1<4>(ax, bUZp, loff, a_cz);
            float zrn[4], zin[4], zan[4];
#pragma unroll
            for (int j = 0; j < 4; ++j) {
                float tz  = fminf(fmaxf(sigmoid_fast(a_tz[j] + btauz), 0.01f), 1.0f) + 1e-6f;
                float rtz = rcp_(tz);
                float dzr = -zr_[j] + tanh_fast(a_tzr[j] + btzr) + a_cz[j] + bzrt;
                float dzi = -zi_[j] + tanh_fast(a_tzi[j] + btzi) + a_cz[j] + bzit;
                zrn[j] = zr_[j] + DT_ * dzr * rtz;
                zin[j] = zi_[j] + DT_ * dzi * rtz;
                zan[j] = sqrtf(zrn[j] * zrn[j] + zin[j] * zin[j] + 1e-24f);
                zr_[j] = zrn[j]; zi_[j] = zin[j];
            }
            size_t base = (((size_t)p * 16 + rg) * 4) * 1024 + (size_t)n * 4 + hi;
            __hip_atomic_store(&sb[base + 1024], pack4(zrn[0], zrn[1], zrn[2], zrn[3]),
                               __ATOMIC_RELAXED, __HIP_MEMORY_SCOPE_AGENT);
            __hip_atomic_store(&sb[base + 2048], pack4(zin[0], zin[1], zin[2], zin[3]),
                               __ATOMIC_RELAXED, __HIP_MEMORY_SCOPE_AGENT);
            __hip_atomic_store(&sb[base + 3072], pack4(zan[0], zan[1], zan[2], zan[3]),
                               __ATOMIC_RELAXED, __HIP_MEMORY_SCOPE_AGENT);
        }
        __syncthreads();   // LDS reads done; publish stores drained; yslot visible

        // ---- inter-barrier window: y store, x prefetch, counter ----
        if (w == 0 && t > 0) {
            f32x4 yz = *(const f32x4*)yslot[lane];
#pragma unroll
            for (int j = 0; j < 4; ++j)
                y[((size_t)(t - 1) * B_ + brow0 + hi * 4 + j) * OUT_ + ny] =
                    a_y[j] + yz[j] + by_;
        }
        if (t + 1 < T_) {
            const float* xrow = x + ((size_t)(t + 1) * B_ + brow0 + m16) * INP_;
#pragma unroll
            for (int kt = 0; kt < 4; ++kt) ax[kt] = loadXfrag(xrow, kt * 32 + hi * 8);
        }
        if (tid == 448) {
            __hip_atomic_fetch_add(ctr, 1u, __ATOMIC_RELAXED, __HIP_MEMORY_SCOPE_AGENT);
            const unsigned tgt = 4u * (unsigned)(t + 1);
            while (__hip_atomic_load(ctr, __ATOMIC_RELAXED, __HIP_MEMORY_SCOPE_AGENT) < tgt)
                __builtin_amdgcn_s_sleep(2);
        }
        __syncthreads();   // all 4 peers published; safe to overwrite sst

        // read full rowgroup state -> LDS (thread: state rsIdx, cols rn0, rn0+1)
        {
            const size_t rb = (((size_t)p * 16 + rg) * 4 + rsIdx) * 1024;
            unsigned long long vb[8];
#pragma unroll
            for (int dn = 0; dn < 2; ++dn)
#pragma unroll
                for (int q = 0; q < 4; ++q)
                    vb[dn * 4 + q] = __hip_atomic_load(&sb[rb + (size_t)(rn0 + dn) * 4 + q],
                                                       __ATOMIC_RELAXED, __HIP_MEMORY_SCOPE_AGENT);
            char* sbase = (char*)sst[rsIdx];
#pragma unroll
            for (int dn = 0; dn < 2; ++dn) {
                const int nc = rn0 + dn;
#pragma unroll
                for (int q = 0; q < 4; ++q) {
                    const unsigned long long v = vb[dn * 4 + q];
#pragma unroll
                    for (int e = 0; e < 4; ++e) {
                        const int r = q * 4 + e;
                        *(unsigned short*)(sbase + ((r * 512 + nc * 2) ^ ((r & 7) << 4))) =
                            (unsigned short)(v >> (e * 16));
                    }
                }
            }
        }
        __syncthreads();   // sst ready for next step
    }

    // final y_{T-1} from S_T (staged in sst by last exchange)
    {
        f32x4 a_y = {0.f, 0.f, 0.f, 0.f};
        if (w == 0) {
            bf16x8 ah[8];
            loadA8(sst[0], m16, hi, ah);
            gemm1<8>(ah, bOHp, loff, a_y);
        }
        if (w == 2) {
            bf16x8 azr[8];
            loadA8(sst[1], m16, hi, azr);
            gemm1<8>(azr, bOZp, loff, a_y);
            *(f32x4*)yslot[lane] = a_y;
        }
        __syncthreads();
        if (w == 0) {
            f32x4 yz = *(const f32x4*)yslot[lane];
#pragma unroll
            for (int j = 0; j < 4; ++j)
                y[((size_t)(T_ - 1) * B_ + brow0 + hi * 4 + j) * OUT_ + ny] =
                    a_y[j] + yz[j] + by_;
        }
    }
}

extern "C" void kernel_launch(void* const* d_in, const int* in_sizes, int n_in,
                              void* d_out, int out_size, void* d_ws, size_t ws_size,
                              hipStream_t stream) {
    const float* x = (const float*)d_in[0];
    unsigned short* ws = (unsigned short*)d_ws;
    float* bias = (float*)((char*)d_ws + BIAS_OFF_BYTES);

    prep_weights<<<(NW_TOTAL / 8 + 255) / 256, 256, 0, stream>>>(
        (const float*)d_in[1],  /* W_h_w */
        (const float*)d_in[5],  /* W_tau_h_w */
        (const float*)d_in[8],  /* W_z_real_w */
        (const float*)d_in[10], /* W_z_imag_w */
        (const float*)d_in[14], /* W_tau_z_w */
        (const float*)d_in[18], /* h2z_w */
        (const float*)d_in[20], /* z2h_w */
        (const float*)d_in[3],  /* U_h_w */
        (const float*)d_in[12], /* U_z_w */
        (const float*)d_in[22], /* out_h_w */
        (const float*)d_in[24], /* out_z_w */
        ws);
    prep_bias<<<1, 256, 0, stream>>>(
        (const float*)d_in[2],  /* W_h_b */
        (const float*)d_in[6],  /* W_tau_h_b */
        (const float*)d_in[4],  /* U_h_b */
        (const float*)d_in[7],  /* b_h */
        (const float*)d_in[21], /* z2h_b */
        (const float*)d_in[9],  /* W_z_real_b */
        (const float*)d_in[11], /* W_z_imag_b */
        (const float*)d_in[15], /* W_tau_z_b */
        (const float*)d_in[13], /* U_z_b */
        (const float*)d_in[16], /* b_z_real */
        (const float*)d_in[17], /* b_z_imag */
        (const float*)d_in[19], /* h2z_b */
        (const float*)d_in[23], /* out_h_b */
        (const float*)d_in[25], /* out_z_b */
        bias);
    twistor_main<<<64, 512, 0, stream>>>(x, ws, (float*)d_out);
}